// Round 1
// baseline (1046.310 us; speedup 1.0000x reference)
//
#include <hip/hip_runtime.h>

#define NNODES 50000
#define NEDGES 800000
#define EPTOT  (NEDGES + NNODES)

static __device__ __forceinline__ float lrelu(float x, float s) { return x > 0.f ? x : s * x; }

__device__ __forceinline__ float wred_max(float v) {
#pragma unroll
  for (int off = 32; off; off >>= 1) v = fmaxf(v, __shfl_xor(v, off));
  return v;
}
__device__ __forceinline__ float wred_sum(float v) {
#pragma unroll
  for (int off = 32; off; off >>= 1) v += __shfl_xor(v, off);
  return v;
}

// ---------------- CSR build ----------------
__global__ void k_hist(const int* __restrict__ adj, int* __restrict__ deg) {
  int i = blockIdx.x * blockDim.x + threadIdx.x;
  if (i >= EPTOT) return;
  int d = (i < NEDGES) ? adj[NEDGES + i] : (i - NEDGES);
  atomicAdd(&deg[d], 1);
}

__global__ __launch_bounds__(1024) void k_scan(const int* __restrict__ deg,
                                               int* __restrict__ rowptr,
                                               int* __restrict__ fill) {
  __shared__ int sm[1024];
  int t = threadIdx.x;
  const int chunk = (NNODES + 1023) / 1024;
  int b = t * chunk;
  int e = min(NNODES, b + chunk);
  if (b > NNODES) b = NNODES;
  int s = 0;
  for (int i = b; i < e; ++i) s += deg[i];
  sm[t] = s;
  __syncthreads();
  for (int off = 1; off < 1024; off <<= 1) {
    int v = (t >= off) ? sm[t - off] : 0;
    __syncthreads();
    sm[t] += v;
    __syncthreads();
  }
  int run = (t > 0) ? sm[t - 1] : 0;
  for (int i = b; i < e; ++i) {
    rowptr[i] = run;
    fill[i] = run;
    run += deg[i];
  }
  if (t == 1023) rowptr[NNODES] = run;
}

__global__ void k_fill(const int* __restrict__ adj, int* __restrict__ fill,
                       int* __restrict__ colx) {
  int i = blockIdx.x * blockDim.x + threadIdx.x;
  if (i >= EPTOT) return;
  int s, d;
  if (i < NEDGES) { s = adj[i]; d = adj[NEDGES + i]; }
  else            { s = i - NEDGES; d = s; }
  int pos = atomicAdd(&fill[d], 1);
  colx[pos] = s;
}

// ---------------- GEMM: C[M,Nc] = A[M,K] @ W[K,Nc] (f32) ----------------
__global__ __launch_bounds__(256) void k_gemm(const float* __restrict__ A,
                                              const float* __restrict__ W,
                                              float* __restrict__ C,
                                              int M, int K, int Nc) {
  __shared__ float As[16][132];
  __shared__ float Ws[16][132];
  int tid = threadIdx.x;
  int tx = tid & 15, ty = tid >> 4;
  int bm = blockIdx.x * 128, bn = blockIdx.y * 128;
  int ar = tid >> 1, ac = (tid & 1) * 8;
  int wr = tid >> 4, wc = (tid & 15) * 8;
  float acc[8][8] = {{0.f}};

  for (int k0 = 0; k0 < K; k0 += 16) {
    float4 a0 = {0, 0, 0, 0}, a1 = {0, 0, 0, 0};
    int arow = bm + ar;
    if (arow < M) {
      const float* ap = A + (size_t)arow * K + k0 + ac;
      a0 = *(const float4*)ap;
      a1 = *(const float4*)(ap + 4);
    }
    As[ac + 0][ar] = a0.x; As[ac + 1][ar] = a0.y;
    As[ac + 2][ar] = a0.z; As[ac + 3][ar] = a0.w;
    As[ac + 4][ar] = a1.x; As[ac + 5][ar] = a1.y;
    As[ac + 6][ar] = a1.z; As[ac + 7][ar] = a1.w;

    float4 w0 = {0, 0, 0, 0}, w1 = {0, 0, 0, 0};
    {
      const float* wp = W + (size_t)(k0 + wr) * Nc;
      int wcol = bn + wc;
      if (wcol + 7 < Nc) {
        w0 = *(const float4*)(wp + wcol);
        w1 = *(const float4*)(wp + wcol + 4);
      } else {
        float t[8];
#pragma unroll
        for (int j = 0; j < 8; ++j) t[j] = (wcol + j < Nc) ? wp[wcol + j] : 0.f;
        w0.x = t[0]; w0.y = t[1]; w0.z = t[2]; w0.w = t[3];
        w1.x = t[4]; w1.y = t[5]; w1.z = t[6]; w1.w = t[7];
      }
    }
    *(float4*)&Ws[wr][wc] = w0;
    *(float4*)&Ws[wr][wc + 4] = w1;
    __syncthreads();

#pragma unroll
    for (int kk = 0; kk < 16; ++kk) {
      float4 pa0 = *(const float4*)&As[kk][ty * 8];
      float4 pa1 = *(const float4*)&As[kk][ty * 8 + 4];
      float4 pb0 = *(const float4*)&Ws[kk][tx * 4];
      float4 pb1 = *(const float4*)&Ws[kk][64 + tx * 4];
      float av[8] = {pa0.x, pa0.y, pa0.z, pa0.w, pa1.x, pa1.y, pa1.z, pa1.w};
      float bv[8] = {pb0.x, pb0.y, pb0.z, pb0.w, pb1.x, pb1.y, pb1.z, pb1.w};
#pragma unroll
      for (int i = 0; i < 8; ++i)
#pragma unroll
        for (int j = 0; j < 8; ++j) acc[i][j] = fmaf(av[i], bv[j], acc[i][j]);
    }
    __syncthreads();
  }

#pragma unroll
  for (int i = 0; i < 8; ++i) {
    int r = bm + ty * 8 + i;
    if (r >= M) continue;
    float* cp = C + (size_t)r * Nc;
    int c0 = bn + tx * 4;
    if (c0 + 3 < Nc) {
      float4 v = {acc[i][0], acc[i][1], acc[i][2], acc[i][3]};
      *(float4*)(cp + c0) = v;
    } else {
#pragma unroll
      for (int j = 0; j < 4; ++j) if (c0 + j < Nc) cp[c0 + j] = acc[i][j];
    }
    int c1 = bn + 64 + tx * 4;
    if (c1 + 3 < Nc) {
      float4 v = {acc[i][4], acc[i][5], acc[i][6], acc[i][7]};
      *(float4*)(cp + c1) = v;
    } else {
#pragma unroll
      for (int j = 0; j < 4; ++j) if (c1 + j < Nc) cp[c1 + j] = acc[i][4 + j];
    }
  }
}

// ---------------- attention coefficients, hidden layers (C=64,H=4) -------------
__global__ __launch_bounds__(256) void k_att_hid(const float* __restrict__ h,
                                                 const float* __restrict__ asw,
                                                 const float* __restrict__ adw,
                                                 float* __restrict__ asrc,
                                                 float* __restrict__ adst) {
  int wid = blockIdx.x * 4 + (threadIdx.x >> 6);
  int lane = threadIdx.x & 63;
  if (wid >= NNODES) return;
  const float* hp = h + (size_t)wid * 256;
  float v0 = hp[lane], v1 = hp[64 + lane], v2 = hp[128 + lane], v3 = hp[192 + lane];
  float ps0 = v0 * asw[lane],       pd0 = v0 * adw[lane];
  float ps1 = v1 * asw[64 + lane],  pd1 = v1 * adw[64 + lane];
  float ps2 = v2 * asw[128 + lane], pd2 = v2 * adw[128 + lane];
  float ps3 = v3 * asw[192 + lane], pd3 = v3 * adw[192 + lane];
  ps0 = wred_sum(ps0); ps1 = wred_sum(ps1); ps2 = wred_sum(ps2); ps3 = wred_sum(ps3);
  pd0 = wred_sum(pd0); pd1 = wred_sum(pd1); pd2 = wred_sum(pd2); pd3 = wred_sum(pd3);
  if (lane == 0) {
    asrc[wid * 4 + 0] = ps0; asrc[wid * 4 + 1] = ps1;
    asrc[wid * 4 + 2] = ps2; asrc[wid * 4 + 3] = ps3;
    adst[wid * 4 + 0] = pd0; adst[wid * 4 + 1] = pd1;
    adst[wid * 4 + 2] = pd2; adst[wid * 4 + 3] = pd3;
  }
}

// ---------------- attention coefficients, layer 2 (C=40,H=4) ----------------
__global__ void k_att_l2(const float* __restrict__ h2, const float* __restrict__ asw,
                         const float* __restrict__ adw, float* __restrict__ asrc,
                         float* __restrict__ adst) {
  int idx = blockIdx.x * blockDim.x + threadIdx.x;
  if (idx >= NNODES * 4) return;
  int node = idx >> 2, hh = idx & 3;
  const float* hp = h2 + (size_t)node * 160 + hh * 40;
  const float* aw = asw + hh * 40;
  const float* dw = adw + hh * 40;
  float s = 0.f, d = 0.f;
#pragma unroll 8
  for (int c = 0; c < 40; ++c) {
    float v = hp[c];
    s = fmaf(v, aw[c], s);
    d = fmaf(v, dw[c], d);
  }
  asrc[idx] = s;
  adst[idx] = d;
}

// ---------------- GAT aggregate, hidden layers: one wave per node -----------
__global__ __launch_bounds__(256) void k_aggr_hid(const float* __restrict__ h,
                                                  const float* __restrict__ asrc,
                                                  const float* __restrict__ adst,
                                                  const int* __restrict__ rowptr,
                                                  const int* __restrict__ colx,
                                                  const float* __restrict__ bias,
                                                  float* __restrict__ out) {
  int wid = blockIdx.x * 4 + (threadIdx.x >> 6);
  int lane = threadIdx.x & 63;
  if (wid >= NNODES) return;
  int beg = rowptr[wid], end = rowptr[wid + 1];
  float ad0 = adst[wid * 4 + 0], ad1 = adst[wid * 4 + 1];
  float ad2 = adst[wid * 4 + 2], ad3 = adst[wid * 4 + 3];

  float m0 = -3.0e38f, m1 = -3.0e38f, m2 = -3.0e38f, m3 = -3.0e38f;
  for (int i = beg + lane; i < end; i += 64) {
    int s = colx[i];
    const float* ap = asrc + (size_t)s * 4;
    m0 = fmaxf(m0, lrelu(ap[0] + ad0, 0.2f));
    m1 = fmaxf(m1, lrelu(ap[1] + ad1, 0.2f));
    m2 = fmaxf(m2, lrelu(ap[2] + ad2, 0.2f));
    m3 = fmaxf(m3, lrelu(ap[3] + ad3, 0.2f));
  }
  m0 = wred_max(m0); m1 = wred_max(m1); m2 = wred_max(m2); m3 = wred_max(m3);

  float s0 = 0.f, s1 = 0.f, s2 = 0.f, s3 = 0.f;
  for (int i = beg + lane; i < end; i += 64) {
    int s = colx[i];
    const float* ap = asrc + (size_t)s * 4;
    s0 += expf(lrelu(ap[0] + ad0, 0.2f) - m0);
    s1 += expf(lrelu(ap[1] + ad1, 0.2f) - m1);
    s2 += expf(lrelu(ap[2] + ad2, 0.2f) - m2);
    s3 += expf(lrelu(ap[3] + ad3, 0.2f) - m3);
  }
  s0 = wred_sum(s0); s1 = wred_sum(s1); s2 = wred_sum(s2); s3 = wred_sum(s3);

  int q = lane >> 4;  // head owning this lane's float4
  float adq = (q == 0) ? ad0 : (q == 1) ? ad1 : (q == 2) ? ad2 : ad3;
  float mq  = (q == 0) ? m0  : (q == 1) ? m1  : (q == 2) ? m2  : m3;
  float sq  = (q == 0) ? s0  : (q == 1) ? s1  : (q == 2) ? s2  : s3;

  float4 acc = {0, 0, 0, 0};
  const float4* h4 = (const float4*)h;
  for (int i = beg; i < end; ++i) {
    int s = colx[i];
    float aq = asrc[(size_t)s * 4 + q];
    float w = expf(lrelu(aq + adq, 0.2f) - mq);
    float4 hv = h4[(size_t)s * 64 + lane];
    acc.x = fmaf(w, hv.x, acc.x);
    acc.y = fmaf(w, hv.y, acc.y);
    acc.z = fmaf(w, hv.z, acc.z);
    acc.w = fmaf(w, hv.w, acc.w);
  }
  float inv = 1.f / (sq + 1e-16f);
  float4 b4 = ((const float4*)bias)[lane];
  float4 o;
  o.x = acc.x * inv + b4.x;
  o.y = acc.y * inv + b4.y;
  o.z = acc.z * inv + b4.z;
  o.w = acc.w * inv + b4.w;
  ((float4*)out)[(size_t)wid * 64 + lane] = o;
}

// ------- layer-2 aggregate + head-mean + bias + log_softmax (fused) ---------
__global__ __launch_bounds__(256) void k_aggr_l2(const float* __restrict__ h2,
                                                 const float* __restrict__ asrc,
                                                 const float* __restrict__ adst,
                                                 const int* __restrict__ rowptr,
                                                 const int* __restrict__ colx,
                                                 const float* __restrict__ b2,
                                                 float* __restrict__ out) {
  __shared__ float tile[4][160];
  int wv = threadIdx.x >> 6;
  int wid = blockIdx.x * 4 + wv;
  int lane = threadIdx.x & 63;
  bool valid = (wid < NNODES);
  int beg = 0, end = 0;
  float ad0 = 0, ad1 = 0, ad2 = 0, ad3 = 0;
  if (valid) {
    beg = rowptr[wid]; end = rowptr[wid + 1];
    ad0 = adst[wid * 4 + 0]; ad1 = adst[wid * 4 + 1];
    ad2 = adst[wid * 4 + 2]; ad3 = adst[wid * 4 + 3];
  }
  float m0 = -3.0e38f, m1 = -3.0e38f, m2 = -3.0e38f, m3 = -3.0e38f;
  for (int i = beg + lane; i < end; i += 64) {
    int s = colx[i];
    const float* ap = asrc + (size_t)s * 4;
    m0 = fmaxf(m0, lrelu(ap[0] + ad0, 0.2f));
    m1 = fmaxf(m1, lrelu(ap[1] + ad1, 0.2f));
    m2 = fmaxf(m2, lrelu(ap[2] + ad2, 0.2f));
    m3 = fmaxf(m3, lrelu(ap[3] + ad3, 0.2f));
  }
  m0 = wred_max(m0); m1 = wred_max(m1); m2 = wred_max(m2); m3 = wred_max(m3);
  float s0 = 0.f, s1 = 0.f, s2 = 0.f, s3 = 0.f;
  for (int i = beg + lane; i < end; i += 64) {
    int s = colx[i];
    const float* ap = asrc + (size_t)s * 4;
    s0 += expf(lrelu(ap[0] + ad0, 0.2f) - m0);
    s1 += expf(lrelu(ap[1] + ad1, 0.2f) - m1);
    s2 += expf(lrelu(ap[2] + ad2, 0.2f) - m2);
    s3 += expf(lrelu(ap[3] + ad3, 0.2f) - m3);
  }
  s0 = wred_sum(s0); s1 = wred_sum(s1); s2 = wred_sum(s2); s3 = wred_sum(s3);

  int q = lane / 10; if (q > 3) q = 3;     // head for lane's float4 (lanes<40)
  float adq = (q == 0) ? ad0 : (q == 1) ? ad1 : (q == 2) ? ad2 : ad3;
  float mq  = (q == 0) ? m0  : (q == 1) ? m1  : (q == 2) ? m2  : m3;
  float sq  = (q == 0) ? s0  : (q == 1) ? s1  : (q == 2) ? s2  : s3;

  float4 acc = {0, 0, 0, 0};
  const float4* g4 = (const float4*)h2;   // row = 40 float4
  for (int i = beg; i < end; ++i) {
    int s = colx[i];
    float aq = asrc[(size_t)s * 4 + q];
    float w = expf(lrelu(aq + adq, 0.2f) - mq);
    if (lane < 40) {
      float4 hv = g4[(size_t)s * 40 + lane];
      acc.x = fmaf(w, hv.x, acc.x);
      acc.y = fmaf(w, hv.y, acc.y);
      acc.z = fmaf(w, hv.z, acc.z);
      acc.w = fmaf(w, hv.w, acc.w);
    }
  }
  if (valid && lane < 40) {
    float inv = 1.f / (sq + 1e-16f);
    tile[wv][lane * 4 + 0] = acc.x * inv;
    tile[wv][lane * 4 + 1] = acc.y * inv;
    tile[wv][lane * 4 + 2] = acc.z * inv;
    tile[wv][lane * 4 + 3] = acc.w * inv;
  }
  __syncthreads();
  int c = lane;
  float val = -3.0e38f;
  if (valid && c < 40) {
    val = 0.25f * (tile[wv][c] + tile[wv][c + 40] + tile[wv][c + 80] + tile[wv][c + 120]) + b2[c];
  }
  float mv = (valid && c < 40) ? val : -3.0e38f;
  mv = wred_max(mv);
  float ex = (valid && c < 40) ? expf(val - mv) : 0.f;
  ex = wred_sum(ex);
  if (valid && c < 40) out[(size_t)wid * 40 + c] = val - mv - logf(ex);
}

// ---------------- batch norm ----------------
__global__ __launch_bounds__(256) void k_bnstats(const float* __restrict__ x,
                                                 float* __restrict__ stat) {
  int c = threadIdx.x;  // 256 channels
  const int rows = (NNODES + gridDim.x - 1) / gridDim.x;
  int r0 = blockIdx.x * rows;
  int r1 = min(NNODES, r0 + rows);
  float s = 0.f, qq = 0.f;
  for (int r = r0; r < r1; ++r) {
    float v = x[(size_t)r * 256 + c];
    s += v;
    qq = fmaf(v, v, qq);
  }
  atomicAdd(&stat[c], s);
  atomicAdd(&stat[256 + c], qq);
}

__global__ void k_bnfin(const float* __restrict__ stat, const float* __restrict__ g,
                        const float* __restrict__ be, float* __restrict__ sc,
                        float* __restrict__ sh) {
  int c = threadIdx.x;
  float mean = stat[c] * (1.0f / NNODES);
  float var = stat[256 + c] * (1.0f / NNODES) - mean * mean;
  float inv = rsqrtf(var + 1e-5f);
  float a = g[c] * inv;
  sc[c] = a;
  sh[c] = be[c] - mean * a;
}

__global__ void k_bnapply(float* __restrict__ x, const float* __restrict__ sc,
                          const float* __restrict__ sh) {
  int idx = blockIdx.x * blockDim.x + threadIdx.x;  // over N*64 float4s
  if (idx >= NNODES * 64) return;
  float4 v = ((float4*)x)[idx];
  int cb = (idx & 63) * 4;
  v.x = lrelu(fmaf(v.x, sc[cb + 0], sh[cb + 0]), 0.1f);
  v.y = lrelu(fmaf(v.y, sc[cb + 1], sh[cb + 1]), 0.1f);
  v.z = lrelu(fmaf(v.z, sc[cb + 2], sh[cb + 2]), 0.1f);
  v.w = lrelu(fmaf(v.w, sc[cb + 3], sh[cb + 3]), 0.1f);
  ((float4*)x)[idx] = v;
}

// ---------------- launch ----------------
extern "C" void kernel_launch(void* const* d_in, const int* in_sizes, int n_in,
                              void* d_out, int out_size, void* d_ws, size_t ws_size,
                              hipStream_t stream) {
  const float* x   = (const float*)d_in[0];
  const int*   adj = (const int*)d_in[1];
  const float* W0  = (const float*)d_in[2];
  const float* as0 = (const float*)d_in[3];
  const float* ad0 = (const float*)d_in[4];
  const float* b0  = (const float*)d_in[5];
  const float* W1  = (const float*)d_in[6];
  const float* as1 = (const float*)d_in[7];
  const float* ad1 = (const float*)d_in[8];
  const float* b1  = (const float*)d_in[9];
  const float* W2  = (const float*)d_in[10];
  const float* as2 = (const float*)d_in[11];
  const float* ad2 = (const float*)d_in[12];
  const float* b2  = (const float*)d_in[13];
  const float* g0  = (const float*)d_in[14];
  const float* be0 = (const float*)d_in[15];
  const float* g1  = (const float*)d_in[16];
  const float* be1 = (const float*)d_in[17];
  float* out = (float*)d_out;

  float* ws   = (float*)d_ws;
  float* buf0 = ws;                                  // N*256
  float* buf1 = buf0 + (size_t)NNODES * 256;         // N*256
  float* asrc = buf1 + (size_t)NNODES * 256;         // N*4
  float* adst = asrc + (size_t)NNODES * 4;           // N*4
  float* stat = adst + (size_t)NNODES * 4;           // 512
  float* bnsc = stat + 512;                          // 256
  float* bnsh = bnsc + 256;                          // 256
  int* rowptr = (int*)(bnsh + 256);                  // N+1
  int* fill   = rowptr + (NNODES + 1);               // N
  int* colx   = fill + NNODES;                       // EPTOT
  int* deg    = colx + EPTOT;                        // N

  // CSR build (by destination), self-loops appended as edges E..E+N-1
  hipMemsetAsync(deg, 0, NNODES * sizeof(int), stream);
  k_hist<<<(EPTOT + 255) / 256, 256, 0, stream>>>(adj, deg);
  k_scan<<<1, 1024, 0, stream>>>(deg, rowptr, fill);
  k_fill<<<(EPTOT + 255) / 256, 256, 0, stream>>>(adj, fill, colx);

  dim3 gg((NNODES + 127) / 128, 2);

  // layer 0
  k_gemm<<<gg, 256, 0, stream>>>(x, W0, buf0, NNODES, 128, 256);
  k_att_hid<<<12500, 256, 0, stream>>>(buf0, as0, ad0, asrc, adst);
  k_aggr_hid<<<12500, 256, 0, stream>>>(buf0, asrc, adst, rowptr, colx, b0, buf1);
  hipMemsetAsync(stat, 0, 512 * sizeof(float), stream);
  k_bnstats<<<400, 256, 0, stream>>>(buf1, stat);
  k_bnfin<<<1, 256, 0, stream>>>(stat, g0, be0, bnsc, bnsh);
  k_bnapply<<<12500, 256, 0, stream>>>(buf1, bnsc, bnsh);

  // layer 1
  k_gemm<<<gg, 256, 0, stream>>>(buf1, W1, buf0, NNODES, 256, 256);
  k_att_hid<<<12500, 256, 0, stream>>>(buf0, as1, ad1, asrc, adst);
  k_aggr_hid<<<12500, 256, 0, stream>>>(buf0, asrc, adst, rowptr, colx, b1, buf1);
  hipMemsetAsync(stat, 0, 512 * sizeof(float), stream);
  k_bnstats<<<400, 256, 0, stream>>>(buf1, stat);
  k_bnfin<<<1, 256, 0, stream>>>(stat, g1, be1, bnsc, bnsh);
  k_bnapply<<<12500, 256, 0, stream>>>(buf1, bnsc, bnsh);

  // layer 2 (heads averaged) + fused log_softmax
  k_gemm<<<gg, 256, 0, stream>>>(buf1, W2, buf0, NNODES, 256, 160);
  k_att_l2<<<(NNODES * 4 + 255) / 256, 256, 0, stream>>>(buf0, as2, ad2, asrc, adst);
  k_aggr_l2<<<12500, 256, 0, stream>>>(buf0, asrc, adst, rowptr, colx, b2, out);
}

// Round 2
// 863.563 us; speedup vs baseline: 1.2116x; 1.2116x over previous
//
#include <hip/hip_runtime.h>

#define NNODES 50000
#define NEDGES 800000
#define EPTOT  (NEDGES + NNODES)

typedef unsigned short u16;
typedef unsigned int   u32;

static __device__ __forceinline__ float lrelu(float x, float s) { return x > 0.f ? x : s * x; }
static __device__ __forceinline__ float bf2f(u16 b) { return __uint_as_float((u32)b << 16); }
static __device__ __forceinline__ u16 f2bf(float f) {
  u32 u = __float_as_uint(f);
  u32 r = (u + 0x7FFFu + ((u >> 16) & 1u)) >> 16;  // round-nearest-even
  return (u16)r;
}

__device__ __forceinline__ float wred_max(float v) {
#pragma unroll
  for (int off = 32; off; off >>= 1) v = fmaxf(v, __shfl_xor(v, off));
  return v;
}
__device__ __forceinline__ float wred_sum(float v) {
#pragma unroll
  for (int off = 32; off; off >>= 1) v += __shfl_xor(v, off);
  return v;
}

// ---------------- CSR build ----------------
__global__ void k_hist(const int* __restrict__ adj, int* __restrict__ deg) {
  int i = blockIdx.x * blockDim.x + threadIdx.x;
  if (i >= EPTOT) return;
  int d = (i < NEDGES) ? adj[NEDGES + i] : (i - NEDGES);
  atomicAdd(&deg[d], 1);
}

__global__ __launch_bounds__(1024) void k_scan(const int* __restrict__ deg,
                                               int* __restrict__ rowptr,
                                               int* __restrict__ fill) {
  __shared__ int sm[1024];
  int t = threadIdx.x;
  const int chunk = (NNODES + 1023) / 1024;
  int b = t * chunk;
  int e = min(NNODES, b + chunk);
  if (b > NNODES) b = NNODES;
  int s = 0;
  for (int i = b; i < e; ++i) s += deg[i];
  sm[t] = s;
  __syncthreads();
  for (int off = 1; off < 1024; off <<= 1) {
    int v = (t >= off) ? sm[t - off] : 0;
    __syncthreads();
    sm[t] += v;
    __syncthreads();
  }
  int run = (t > 0) ? sm[t - 1] : 0;
  for (int i = b; i < e; ++i) {
    rowptr[i] = run;
    fill[i] = run;
    run += deg[i];
  }
  if (t == 1023) rowptr[NNODES] = run;
}

__global__ void k_fill(const int* __restrict__ adj, int* __restrict__ fill,
                       int* __restrict__ colx) {
  int i = blockIdx.x * blockDim.x + threadIdx.x;
  if (i >= EPTOT) return;
  int s, d;
  if (i < NEDGES) { s = adj[i]; d = adj[NEDGES + i]; }
  else            { s = i - NEDGES; d = s; }
  int pos = atomicAdd(&fill[d], 1);
  colx[pos] = s;
}

// -------- GEMM: Cb[M,Nc](bf16) = A[M,K](f32) @ W[K,Nc](f32) --------
__global__ __launch_bounds__(256) void k_gemm(const float* __restrict__ A,
                                              const float* __restrict__ W,
                                              u16* __restrict__ Cb,
                                              int M, int K, int Nc) {
  __shared__ float As[16][132];
  __shared__ float Ws[16][132];
  int tid = threadIdx.x;
  int tx = tid & 15, ty = tid >> 4;
  int bm = blockIdx.x * 128, bn = blockIdx.y * 128;
  int ar = tid >> 1, ac = (tid & 1) * 8;
  int wr = tid >> 4, wc = (tid & 15) * 8;
  float acc[8][8] = {{0.f}};

  for (int k0 = 0; k0 < K; k0 += 16) {
    float4 a0 = {0, 0, 0, 0}, a1 = {0, 0, 0, 0};
    int arow = bm + ar;
    if (arow < M) {
      const float* ap = A + (size_t)arow * K + k0 + ac;
      a0 = *(const float4*)ap;
      a1 = *(const float4*)(ap + 4);
    }
    As[ac + 0][ar] = a0.x; As[ac + 1][ar] = a0.y;
    As[ac + 2][ar] = a0.z; As[ac + 3][ar] = a0.w;
    As[ac + 4][ar] = a1.x; As[ac + 5][ar] = a1.y;
    As[ac + 6][ar] = a1.z; As[ac + 7][ar] = a1.w;

    float4 w0 = {0, 0, 0, 0}, w1 = {0, 0, 0, 0};
    {
      const float* wp = W + (size_t)(k0 + wr) * Nc;
      int wcol = bn + wc;
      if (wcol + 7 < Nc) {
        w0 = *(const float4*)(wp + wcol);
        w1 = *(const float4*)(wp + wcol + 4);
      } else {
        float t[8];
#pragma unroll
        for (int j = 0; j < 8; ++j) t[j] = (wcol + j < Nc) ? wp[wcol + j] : 0.f;
        w0.x = t[0]; w0.y = t[1]; w0.z = t[2]; w0.w = t[3];
        w1.x = t[4]; w1.y = t[5]; w1.z = t[6]; w1.w = t[7];
      }
    }
    *(float4*)&Ws[wr][wc] = w0;
    *(float4*)&Ws[wr][wc + 4] = w1;
    __syncthreads();

#pragma unroll
    for (int kk = 0; kk < 16; ++kk) {
      float4 pa0 = *(const float4*)&As[kk][ty * 8];
      float4 pa1 = *(const float4*)&As[kk][ty * 8 + 4];
      float4 pb0 = *(const float4*)&Ws[kk][tx * 4];
      float4 pb1 = *(const float4*)&Ws[kk][64 + tx * 4];
      float av[8] = {pa0.x, pa0.y, pa0.z, pa0.w, pa1.x, pa1.y, pa1.z, pa1.w};
      float bv[8] = {pb0.x, pb0.y, pb0.z, pb0.w, pb1.x, pb1.y, pb1.z, pb1.w};
#pragma unroll
      for (int i = 0; i < 8; ++i)
#pragma unroll
        for (int j = 0; j < 8; ++j) acc[i][j] = fmaf(av[i], bv[j], acc[i][j]);
    }
    __syncthreads();
  }

#pragma unroll
  for (int i = 0; i < 8; ++i) {
    int r = bm + ty * 8 + i;
    if (r >= M) continue;
    u16* cp = Cb + (size_t)r * Nc;
    int c0 = bn + tx * 4;
    if (c0 + 3 < Nc) {
      ushort4 v = {f2bf(acc[i][0]), f2bf(acc[i][1]), f2bf(acc[i][2]), f2bf(acc[i][3])};
      *(ushort4*)(cp + c0) = v;
    } else {
#pragma unroll
      for (int j = 0; j < 4; ++j) if (c0 + j < Nc) cp[c0 + j] = f2bf(acc[i][j]);
    }
    int c1 = bn + 64 + tx * 4;
    if (c1 + 3 < Nc) {
      ushort4 v = {f2bf(acc[i][4]), f2bf(acc[i][5]), f2bf(acc[i][6]), f2bf(acc[i][7])};
      *(ushort4*)(cp + c1) = v;
    } else {
#pragma unroll
      for (int j = 0; j < 4; ++j) if (c1 + j < Nc) cp[c1 + j] = f2bf(acc[i][4 + j]);
    }
  }
}

// ------------ attention coefficients, hidden layers (C=64,H=4) ------------
__global__ __launch_bounds__(256) void k_att_hid(const u16* __restrict__ hb,
                                                 const float* __restrict__ asw,
                                                 const float* __restrict__ adw,
                                                 float* __restrict__ asrc,
                                                 float* __restrict__ adst) {
  int wid = blockIdx.x * 4 + (threadIdx.x >> 6);
  int lane = threadIdx.x & 63;
  if (wid >= NNODES) return;
  const u16* hp = hb + (size_t)wid * 256;
  float v0 = bf2f(hp[lane]), v1 = bf2f(hp[64 + lane]);
  float v2 = bf2f(hp[128 + lane]), v3 = bf2f(hp[192 + lane]);
  float ps0 = v0 * asw[lane],       pd0 = v0 * adw[lane];
  float ps1 = v1 * asw[64 + lane],  pd1 = v1 * adw[64 + lane];
  float ps2 = v2 * asw[128 + lane], pd2 = v2 * adw[128 + lane];
  float ps3 = v3 * asw[192 + lane], pd3 = v3 * adw[192 + lane];
  ps0 = wred_sum(ps0); ps1 = wred_sum(ps1); ps2 = wred_sum(ps2); ps3 = wred_sum(ps3);
  pd0 = wred_sum(pd0); pd1 = wred_sum(pd1); pd2 = wred_sum(pd2); pd3 = wred_sum(pd3);
  if (lane == 0) {
    asrc[wid * 4 + 0] = ps0; asrc[wid * 4 + 1] = ps1;
    asrc[wid * 4 + 2] = ps2; asrc[wid * 4 + 3] = ps3;
    adst[wid * 4 + 0] = pd0; adst[wid * 4 + 1] = pd1;
    adst[wid * 4 + 2] = pd2; adst[wid * 4 + 3] = pd3;
  }
}

// ------------ attention coefficients, layer 2 (C=40,H=4) ------------
__global__ __launch_bounds__(256) void k_att_l2(const u16* __restrict__ hb2,
                                                const float* __restrict__ asw,
                                                const float* __restrict__ adw,
                                                float* __restrict__ asrc,
                                                float* __restrict__ adst) {
  int wid = blockIdx.x * 4 + (threadIdx.x >> 6);
  int lane = threadIdx.x & 63;
  if (wid >= NNODES) return;
  const u16* hp = hb2 + (size_t)wid * 160;
  float ps0 = 0, ps1 = 0, ps2 = 0, ps3 = 0, pd0 = 0, pd1 = 0, pd2 = 0, pd3 = 0;
  if (lane < 40) {
    float v0 = bf2f(hp[lane]), v1 = bf2f(hp[40 + lane]);
    float v2 = bf2f(hp[80 + lane]), v3 = bf2f(hp[120 + lane]);
    ps0 = v0 * asw[lane];       pd0 = v0 * adw[lane];
    ps1 = v1 * asw[40 + lane];  pd1 = v1 * adw[40 + lane];
    ps2 = v2 * asw[80 + lane];  pd2 = v2 * adw[80 + lane];
    ps3 = v3 * asw[120 + lane]; pd3 = v3 * adw[120 + lane];
  }
  ps0 = wred_sum(ps0); ps1 = wred_sum(ps1); ps2 = wred_sum(ps2); ps3 = wred_sum(ps3);
  pd0 = wred_sum(pd0); pd1 = wred_sum(pd1); pd2 = wred_sum(pd2); pd3 = wred_sum(pd3);
  if (lane == 0) {
    asrc[wid * 4 + 0] = ps0; asrc[wid * 4 + 1] = ps1;
    asrc[wid * 4 + 2] = ps2; asrc[wid * 4 + 3] = ps3;
    adst[wid * 4 + 0] = pd0; adst[wid * 4 + 1] = pd1;
    adst[wid * 4 + 2] = pd2; adst[wid * 4 + 3] = pd3;
  }
}

// ---------- GAT aggregate, hidden layers: one wave per node ----------
__global__ __launch_bounds__(256) void k_aggr_hid(const u16* __restrict__ hb,
                                                  const float* __restrict__ asrc,
                                                  const float* __restrict__ adst,
                                                  const int* __restrict__ rowptr,
                                                  const int* __restrict__ colx,
                                                  const float* __restrict__ bias,
                                                  float* __restrict__ out) {
  int wid = blockIdx.x * 4 + (threadIdx.x >> 6);
  int lane = threadIdx.x & 63;
  if (wid >= NNODES) return;
  int beg = rowptr[wid], end = rowptr[wid + 1];
  float ad0 = adst[wid * 4 + 0], ad1 = adst[wid * 4 + 1];
  float ad2 = adst[wid * 4 + 2], ad3 = adst[wid * 4 + 3];

  // softmax denominators (shift-invariant: no max subtraction, logits ~ O(10))
  float s0 = 0.f, s1 = 0.f, s2 = 0.f, s3 = 0.f;
  for (int i = beg + lane; i < end; i += 64) {
    int s = colx[i];
    const float* ap = asrc + (size_t)s * 4;
    s0 += expf(lrelu(ap[0] + ad0, 0.2f));
    s1 += expf(lrelu(ap[1] + ad1, 0.2f));
    s2 += expf(lrelu(ap[2] + ad2, 0.2f));
    s3 += expf(lrelu(ap[3] + ad3, 0.2f));
  }
  s0 = wred_sum(s0); s1 = wred_sum(s1); s2 = wred_sum(s2); s3 = wred_sum(s3);

  int q = lane >> 4;  // head owning this lane's 4 channels
  float adq = (q == 0) ? ad0 : (q == 1) ? ad1 : (q == 2) ? ad2 : ad3;
  float sq  = (q == 0) ? s0  : (q == 1) ? s1  : (q == 2) ? s2  : s3;

  float ax = 0.f, ay = 0.f, az = 0.f, aw = 0.f;
  const u16* hbl = hb + lane * 4;
  int i = beg;
  for (; i + 4 <= end; i += 4) {
    int e0 = colx[i], e1 = colx[i + 1], e2 = colx[i + 2], e3 = colx[i + 3];
    float w0 = expf(lrelu(asrc[(size_t)e0 * 4 + q] + adq, 0.2f));
    float w1 = expf(lrelu(asrc[(size_t)e1 * 4 + q] + adq, 0.2f));
    float w2 = expf(lrelu(asrc[(size_t)e2 * 4 + q] + adq, 0.2f));
    float w3 = expf(lrelu(asrc[(size_t)e3 * 4 + q] + adq, 0.2f));
    ushort4 r0 = *(const ushort4*)(hbl + (size_t)e0 * 256);
    ushort4 r1 = *(const ushort4*)(hbl + (size_t)e1 * 256);
    ushort4 r2 = *(const ushort4*)(hbl + (size_t)e2 * 256);
    ushort4 r3 = *(const ushort4*)(hbl + (size_t)e3 * 256);
    ax = fmaf(w0, bf2f(r0.x), ax); ay = fmaf(w0, bf2f(r0.y), ay);
    az = fmaf(w0, bf2f(r0.z), az); aw = fmaf(w0, bf2f(r0.w), aw);
    ax = fmaf(w1, bf2f(r1.x), ax); ay = fmaf(w1, bf2f(r1.y), ay);
    az = fmaf(w1, bf2f(r1.z), az); aw = fmaf(w1, bf2f(r1.w), aw);
    ax = fmaf(w2, bf2f(r2.x), ax); ay = fmaf(w2, bf2f(r2.y), ay);
    az = fmaf(w2, bf2f(r2.z), az); aw = fmaf(w2, bf2f(r2.w), aw);
    ax = fmaf(w3, bf2f(r3.x), ax); ay = fmaf(w3, bf2f(r3.y), ay);
    az = fmaf(w3, bf2f(r3.z), az); aw = fmaf(w3, bf2f(r3.w), aw);
  }
  for (; i < end; ++i) {
    int e0 = colx[i];
    float w0 = expf(lrelu(asrc[(size_t)e0 * 4 + q] + adq, 0.2f));
    ushort4 r0 = *(const ushort4*)(hbl + (size_t)e0 * 256);
    ax = fmaf(w0, bf2f(r0.x), ax); ay = fmaf(w0, bf2f(r0.y), ay);
    az = fmaf(w0, bf2f(r0.z), az); aw = fmaf(w0, bf2f(r0.w), aw);
  }
  float inv = 1.f / (sq + 1e-16f);
  float4 b4 = ((const float4*)bias)[lane];
  float4 o = {fmaf(ax, inv, b4.x), fmaf(ay, inv, b4.y),
              fmaf(az, inv, b4.z), fmaf(aw, inv, b4.w)};
  ((float4*)out)[(size_t)wid * 64 + lane] = o;
}

// ---- layer-2 aggregate + head-mean + bias + log_softmax (fused) ----
__global__ __launch_bounds__(256) void k_aggr_l2(const u16* __restrict__ hb2,
                                                 const float* __restrict__ asrc,
                                                 const float* __restrict__ adst,
                                                 const int* __restrict__ rowptr,
                                                 const int* __restrict__ colx,
                                                 const float* __restrict__ b2,
                                                 float* __restrict__ out) {
  __shared__ float tile[4][160];
  int wv = threadIdx.x >> 6;
  int wid = blockIdx.x * 4 + wv;
  int lane = threadIdx.x & 63;
  bool valid = (wid < NNODES);
  int beg = 0, end = 0;
  float ad0 = 0, ad1 = 0, ad2 = 0, ad3 = 0;
  if (valid) {
    beg = rowptr[wid]; end = rowptr[wid + 1];
    ad0 = adst[wid * 4 + 0]; ad1 = adst[wid * 4 + 1];
    ad2 = adst[wid * 4 + 2]; ad3 = adst[wid * 4 + 3];
  }
  float s0 = 0.f, s1 = 0.f, s2 = 0.f, s3 = 0.f;
  for (int i = beg + lane; i < end; i += 64) {
    int s = colx[i];
    const float* ap = asrc + (size_t)s * 4;
    s0 += expf(lrelu(ap[0] + ad0, 0.2f));
    s1 += expf(lrelu(ap[1] + ad1, 0.2f));
    s2 += expf(lrelu(ap[2] + ad2, 0.2f));
    s3 += expf(lrelu(ap[3] + ad3, 0.2f));
  }
  s0 = wred_sum(s0); s1 = wred_sum(s1); s2 = wred_sum(s2); s3 = wred_sum(s3);

  int q = lane / 10; if (q > 3) q = 3;  // head for this lane's 4 channels (lanes<40)
  float adq = (q == 0) ? ad0 : (q == 1) ? ad1 : (q == 2) ? ad2 : ad3;
  float sq  = (q == 0) ? s0  : (q == 1) ? s1  : (q == 2) ? s2  : s3;

  float ax = 0.f, ay = 0.f, az = 0.f, aw = 0.f;
  const u16* hbl = hb2 + lane * 4;
  int i = beg;
  for (; i + 4 <= end; i += 4) {
    int e0 = colx[i], e1 = colx[i + 1], e2 = colx[i + 2], e3 = colx[i + 3];
    float w0 = expf(lrelu(asrc[(size_t)e0 * 4 + q] + adq, 0.2f));
    float w1 = expf(lrelu(asrc[(size_t)e1 * 4 + q] + adq, 0.2f));
    float w2 = expf(lrelu(asrc[(size_t)e2 * 4 + q] + adq, 0.2f));
    float w3 = expf(lrelu(asrc[(size_t)e3 * 4 + q] + adq, 0.2f));
    if (lane < 40) {
      ushort4 r0 = *(const ushort4*)(hbl + (size_t)e0 * 160);
      ushort4 r1 = *(const ushort4*)(hbl + (size_t)e1 * 160);
      ushort4 r2 = *(const ushort4*)(hbl + (size_t)e2 * 160);
      ushort4 r3 = *(const ushort4*)(hbl + (size_t)e3 * 160);
      ax = fmaf(w0, bf2f(r0.x), ax); ay = fmaf(w0, bf2f(r0.y), ay);
      az = fmaf(w0, bf2f(r0.z), az); aw = fmaf(w0, bf2f(r0.w), aw);
      ax = fmaf(w1, bf2f(r1.x), ax); ay = fmaf(w1, bf2f(r1.y), ay);
      az = fmaf(w1, bf2f(r1.z), az); aw = fmaf(w1, bf2f(r1.w), aw);
      ax = fmaf(w2, bf2f(r2.x), ax); ay = fmaf(w2, bf2f(r2.y), ay);
      az = fmaf(w2, bf2f(r2.z), az); aw = fmaf(w2, bf2f(r2.w), aw);
      ax = fmaf(w3, bf2f(r3.x), ax); ay = fmaf(w3, bf2f(r3.y), ay);
      az = fmaf(w3, bf2f(r3.z), az); aw = fmaf(w3, bf2f(r3.w), aw);
    }
  }
  for (; i < end; ++i) {
    int e0 = colx[i];
    float w0 = expf(lrelu(asrc[(size_t)e0 * 4 + q] + adq, 0.2f));
    if (lane < 40) {
      ushort4 r0 = *(const ushort4*)(hbl + (size_t)e0 * 160);
      ax = fmaf(w0, bf2f(r0.x), ax); ay = fmaf(w0, bf2f(r0.y), ay);
      az = fmaf(w0, bf2f(r0.z), az); aw = fmaf(w0, bf2f(r0.w), aw);
    }
  }
  if (valid && lane < 40) {
    float inv = 1.f / (sq + 1e-16f);
    tile[wv][lane * 4 + 0] = ax * inv;
    tile[wv][lane * 4 + 1] = ay * inv;
    tile[wv][lane * 4 + 2] = az * inv;
    tile[wv][lane * 4 + 3] = aw * inv;
  }
  __syncthreads();
  int c = lane;
  float val = -3.0e38f;
  if (valid && c < 40) {
    val = 0.25f * (tile[wv][c] + tile[wv][c + 40] + tile[wv][c + 80] + tile[wv][c + 120]) + b2[c];
  }
  float mv = (valid && c < 40) ? val : -3.0e38f;
  mv = wred_max(mv);
  float ex = (valid && c < 40) ? expf(val - mv) : 0.f;
  ex = wred_sum(ex);
  if (valid && c < 40) out[(size_t)wid * 40 + c] = val - mv - logf(ex);
}

// ---------------- batch norm ----------------
__global__ __launch_bounds__(256) void k_bnstats(const float* __restrict__ x,
                                                 float* __restrict__ stat) {
  int c = threadIdx.x;  // 256 channels
  const int rows = (NNODES + gridDim.x - 1) / gridDim.x;
  int r0 = blockIdx.x * rows;
  int r1 = min(NNODES, r0 + rows);
  float s = 0.f, qq = 0.f;
  for (int r = r0; r < r1; ++r) {
    float v = x[(size_t)r * 256 + c];
    s += v;
    qq = fmaf(v, v, qq);
  }
  atomicAdd(&stat[c], s);
  atomicAdd(&stat[256 + c], qq);
}

__global__ void k_bnfin(const float* __restrict__ stat, const float* __restrict__ g,
                        const float* __restrict__ be, float* __restrict__ sc,
                        float* __restrict__ sh) {
  int c = threadIdx.x;
  float mean = stat[c] * (1.0f / NNODES);
  float var = stat[256 + c] * (1.0f / NNODES) - mean * mean;
  float inv = rsqrtf(var + 1e-5f);
  float a = g[c] * inv;
  sc[c] = a;
  sh[c] = be[c] - mean * a;
}

__global__ void k_bnapply(float* __restrict__ x, const float* __restrict__ sc,
                          const float* __restrict__ sh) {
  int idx = blockIdx.x * blockDim.x + threadIdx.x;  // over N*64 float4s
  if (idx >= NNODES * 64) return;
  float4 v = ((float4*)x)[idx];
  int cb = (idx & 63) * 4;
  v.x = lrelu(fmaf(v.x, sc[cb + 0], sh[cb + 0]), 0.1f);
  v.y = lrelu(fmaf(v.y, sc[cb + 1], sh[cb + 1]), 0.1f);
  v.z = lrelu(fmaf(v.z, sc[cb + 2], sh[cb + 2]), 0.1f);
  v.w = lrelu(fmaf(v.w, sc[cb + 3], sh[cb + 3]), 0.1f);
  ((float4*)x)[idx] = v;
}

// ---------------- launch ----------------
extern "C" void kernel_launch(void* const* d_in, const int* in_sizes, int n_in,
                              void* d_out, int out_size, void* d_ws, size_t ws_size,
                              hipStream_t stream) {
  const float* x   = (const float*)d_in[0];
  const int*   adj = (const int*)d_in[1];
  const float* W0  = (const float*)d_in[2];
  const float* as0 = (const float*)d_in[3];
  const float* ad0 = (const float*)d_in[4];
  const float* b0  = (const float*)d_in[5];
  const float* W1  = (const float*)d_in[6];
  const float* as1 = (const float*)d_in[7];
  const float* ad1 = (const float*)d_in[8];
  const float* b1  = (const float*)d_in[9];
  const float* W2  = (const float*)d_in[10];
  const float* as2 = (const float*)d_in[11];
  const float* ad2 = (const float*)d_in[12];
  const float* b2  = (const float*)d_in[13];
  const float* g0  = (const float*)d_in[14];
  const float* be0 = (const float*)d_in[15];
  const float* g1  = (const float*)d_in[16];
  const float* be1 = (const float*)d_in[17];
  float* out = (float*)d_out;

  float* ws   = (float*)d_ws;
  float* bufA = ws;                                  // N*256 f32 (agg / post-BN)
  float* asrc = bufA + (size_t)NNODES * 256;         // N*4
  float* adst = asrc + (size_t)NNODES * 4;           // N*4
  float* stat = adst + (size_t)NNODES * 4;           // 512
  float* bnsc = stat + 512;                          // 256
  float* bnsh = bnsc + 256;                          // 256
  u16*   hb   = (u16*)(bnsh + 256);                  // N*256 bf16 (h payload)
  int* rowptr = (int*)(hb + (size_t)NNODES * 256);   // N+1
  int* fill   = rowptr + (NNODES + 1);               // N
  int* colx   = fill + NNODES;                       // EPTOT
  int* deg    = colx + EPTOT;                        // N

  // CSR build (by destination), self-loops appended as edges E..E+N-1
  hipMemsetAsync(deg, 0, NNODES * sizeof(int), stream);
  k_hist<<<(EPTOT + 255) / 256, 256, 0, stream>>>(adj, deg);
  k_scan<<<1, 1024, 0, stream>>>(deg, rowptr, fill);
  k_fill<<<(EPTOT + 255) / 256, 256, 0, stream>>>(adj, fill, colx);

  dim3 gg((NNODES + 127) / 128, 2);

  // layer 0
  k_gemm<<<gg, 256, 0, stream>>>(x, W0, hb, NNODES, 128, 256);
  k_att_hid<<<12500, 256, 0, stream>>>(hb, as0, ad0, asrc, adst);
  k_aggr_hid<<<12500, 256, 0, stream>>>(hb, asrc, adst, rowptr, colx, b0, bufA);
  hipMemsetAsync(stat, 0, 512 * sizeof(float), stream);
  k_bnstats<<<400, 256, 0, stream>>>(bufA, stat);
  k_bnfin<<<1, 256, 0, stream>>>(stat, g0, be0, bnsc, bnsh);
  k_bnapply<<<12500, 256, 0, stream>>>(bufA, bnsc, bnsh);

  // layer 1
  k_gemm<<<gg, 256, 0, stream>>>(bufA, W1, hb, NNODES, 256, 256);
  k_att_hid<<<12500, 256, 0, stream>>>(hb, as1, ad1, asrc, adst);
  k_aggr_hid<<<12500, 256, 0, stream>>>(hb, asrc, adst, rowptr, colx, b1, bufA);
  hipMemsetAsync(stat, 0, 512 * sizeof(float), stream);
  k_bnstats<<<400, 256, 0, stream>>>(bufA, stat);
  k_bnfin<<<1, 256, 0, stream>>>(stat, g1, be1, bnsc, bnsh);
  k_bnapply<<<12500, 256, 0, stream>>>(bufA, bnsc, bnsh);

  // layer 2 (heads averaged) + fused log_softmax
  k_gemm<<<gg, 256, 0, stream>>>(bufA, W2, hb, NNODES, 256, 160);
  k_att_l2<<<12500, 256, 0, stream>>>(hb, as2, ad2, asrc, adst);
  k_aggr_l2<<<12500, 256, 0, stream>>>(hb, asrc, adst, rowptr, colx, b2, out);
}

// Round 3
// 761.239 us; speedup vs baseline: 1.3745x; 1.1344x over previous
//
#include <hip/hip_runtime.h>

#define NNODES 50000
#define NEDGES 800000
#define EPTOT  (NEDGES + NNODES)
#define SCAN_NB ((NNODES + 255) / 256)

typedef unsigned short u16;
typedef unsigned int   u32;

static __device__ __forceinline__ float lrelu(float x, float s) { return x > 0.f ? x : s * x; }
static __device__ __forceinline__ float bf2f(u16 b) { return __uint_as_float((u32)b << 16); }
static __device__ __forceinline__ u16 f2bf(float f) {
  u32 u = __float_as_uint(f);
  u32 r = (u + 0x7FFFu + ((u >> 16) & 1u)) >> 16;  // round-nearest-even
  return (u16)r;
}

__device__ __forceinline__ float wred_max(float v) {
#pragma unroll
  for (int off = 32; off; off >>= 1) v = fmaxf(v, __shfl_xor(v, off));
  return v;
}
__device__ __forceinline__ float wred_sum(float v) {
#pragma unroll
  for (int off = 32; off; off >>= 1) v += __shfl_xor(v, off);
  return v;
}

// ---------------- CSR build ----------------
__global__ void k_hist(const int* __restrict__ adj, int* __restrict__ deg) {
  int i = blockIdx.x * blockDim.x + threadIdx.x;
  if (i >= EPTOT) return;
  int d = (i < NEDGES) ? adj[NEDGES + i] : (i - NEDGES);
  atomicAdd(&deg[d], 1);
}

// multi-block exclusive scan of deg[] (3 tiny kernels)
__global__ __launch_bounds__(256) void k_scan1(const int* __restrict__ deg,
                                               int* __restrict__ part,
                                               int* __restrict__ bsum) {
  __shared__ int sm[256];
  int t = threadIdx.x;
  int i = blockIdx.x * 256 + t;
  int v = (i < NNODES) ? deg[i] : 0;
  sm[t] = v;
  __syncthreads();
#pragma unroll
  for (int off = 1; off < 256; off <<= 1) {
    int u = (t >= off) ? sm[t - off] : 0;
    __syncthreads();
    sm[t] += u;
    __syncthreads();
  }
  if (i < NNODES) part[i] = sm[t] - v;  // exclusive within block
  if (t == 255) bsum[blockIdx.x] = sm[255];
}

__global__ __launch_bounds__(256) void k_scan2(int* __restrict__ bsum) {
  __shared__ int sm[256];
  int t = threadIdx.x;
  int v = (t < SCAN_NB) ? bsum[t] : 0;
  sm[t] = v;
  __syncthreads();
#pragma unroll
  for (int off = 1; off < 256; off <<= 1) {
    int u = (t >= off) ? sm[t - off] : 0;
    __syncthreads();
    sm[t] += u;
    __syncthreads();
  }
  if (t < SCAN_NB) bsum[t] = sm[t] - v;  // exclusive block offsets
}

__global__ __launch_bounds__(256) void k_scan3(const int* __restrict__ part,
                                               const int* __restrict__ bsum,
                                               int* __restrict__ rowptr,
                                               int* __restrict__ fill) {
  int i = blockIdx.x * 256 + threadIdx.x;
  if (i == 0) rowptr[NNODES] = EPTOT;  // total degree is a compile-time constant
  if (i >= NNODES) return;
  int r = part[i] + bsum[blockIdx.x];
  rowptr[i] = r;
  fill[i] = r;
}

__global__ void k_fill(const int* __restrict__ adj, int* __restrict__ fill,
                       int* __restrict__ colx) {
  int i = blockIdx.x * blockDim.x + threadIdx.x;
  if (i >= EPTOT) return;
  int s, d;
  if (i < NEDGES) { s = adj[i]; d = adj[NEDGES + i]; }
  else            { s = i - NEDGES; d = s; }
  int pos = atomicAdd(&fill[d], 1);
  colx[pos] = s;
}

// -------- GEMM: Cb[M,Nc](bf16) = A[M,K](f32) @ W[K,Nc](f32) --------
__global__ __launch_bounds__(256) void k_gemm(const float* __restrict__ A,
                                              const float* __restrict__ W,
                                              u16* __restrict__ Cb,
                                              int M, int K, int Nc) {
  __shared__ float As[16][132];
  __shared__ float Ws[16][132];
  int tid = threadIdx.x;
  int tx = tid & 15, ty = tid >> 4;
  int bm = blockIdx.x * 128, bn = blockIdx.y * 128;
  int ar = tid >> 1, ac = (tid & 1) * 8;
  int wr = tid >> 4, wc = (tid & 15) * 8;
  float acc[8][8] = {{0.f}};

  for (int k0 = 0; k0 < K; k0 += 16) {
    float4 a0 = {0, 0, 0, 0}, a1 = {0, 0, 0, 0};
    int arow = bm + ar;
    if (arow < M) {
      const float* ap = A + (size_t)arow * K + k0 + ac;
      a0 = *(const float4*)ap;
      a1 = *(const float4*)(ap + 4);
    }
    As[ac + 0][ar] = a0.x; As[ac + 1][ar] = a0.y;
    As[ac + 2][ar] = a0.z; As[ac + 3][ar] = a0.w;
    As[ac + 4][ar] = a1.x; As[ac + 5][ar] = a1.y;
    As[ac + 6][ar] = a1.z; As[ac + 7][ar] = a1.w;

    float4 w0 = {0, 0, 0, 0}, w1 = {0, 0, 0, 0};
    {
      const float* wp = W + (size_t)(k0 + wr) * Nc;
      int wcol = bn + wc;
      if (wcol + 7 < Nc) {
        w0 = *(const float4*)(wp + wcol);
        w1 = *(const float4*)(wp + wcol + 4);
      } else {
        float t[8];
#pragma unroll
        for (int j = 0; j < 8; ++j) t[j] = (wcol + j < Nc) ? wp[wcol + j] : 0.f;
        w0.x = t[0]; w0.y = t[1]; w0.z = t[2]; w0.w = t[3];
        w1.x = t[4]; w1.y = t[5]; w1.z = t[6]; w1.w = t[7];
      }
    }
    *(float4*)&Ws[wr][wc] = w0;
    *(float4*)&Ws[wr][wc + 4] = w1;
    __syncthreads();

#pragma unroll
    for (int kk = 0; kk < 16; ++kk) {
      float4 pa0 = *(const float4*)&As[kk][ty * 8];
      float4 pa1 = *(const float4*)&As[kk][ty * 8 + 4];
      float4 pb0 = *(const float4*)&Ws[kk][tx * 4];
      float4 pb1 = *(const float4*)&Ws[kk][64 + tx * 4];
      float av[8] = {pa0.x, pa0.y, pa0.z, pa0.w, pa1.x, pa1.y, pa1.z, pa1.w};
      float bv[8] = {pb0.x, pb0.y, pb0.z, pb0.w, pb1.x, pb1.y, pb1.z, pb1.w};
#pragma unroll
      for (int i = 0; i < 8; ++i)
#pragma unroll
        for (int j = 0; j < 8; ++j) acc[i][j] = fmaf(av[i], bv[j], acc[i][j]);
    }
    __syncthreads();
  }

#pragma unroll
  for (int i = 0; i < 8; ++i) {
    int r = bm + ty * 8 + i;
    if (r >= M) continue;
    u16* cp = Cb + (size_t)r * Nc;
    int c0 = bn + tx * 4;
    if (c0 + 3 < Nc) {
      ushort4 v = {f2bf(acc[i][0]), f2bf(acc[i][1]), f2bf(acc[i][2]), f2bf(acc[i][3])};
      *(ushort4*)(cp + c0) = v;
    } else {
#pragma unroll
      for (int j = 0; j < 4; ++j) if (c0 + j < Nc) cp[c0 + j] = f2bf(acc[i][j]);
    }
    int c1 = bn + 64 + tx * 4;
    if (c1 + 3 < Nc) {
      ushort4 v = {f2bf(acc[i][4]), f2bf(acc[i][5]), f2bf(acc[i][6]), f2bf(acc[i][7])};
      *(ushort4*)(cp + c1) = v;
    } else {
#pragma unroll
      for (int j = 0; j < 4; ++j) if (c1 + j < Nc) cp[c1 + j] = f2bf(acc[i][4 + j]);
    }
  }
}

// ------------ attention coefficients, hidden layers (C=64,H=4) ------------
__global__ __launch_bounds__(256) void k_att_hid(const u16* __restrict__ hb,
                                                 const float* __restrict__ asw,
                                                 const float* __restrict__ adw,
                                                 float* __restrict__ asrc,
                                                 float* __restrict__ adst) {
  int wid = blockIdx.x * 4 + (threadIdx.x >> 6);
  int lane = threadIdx.x & 63;
  if (wid >= NNODES) return;
  const u16* hp = hb + (size_t)wid * 256;
  float v0 = bf2f(hp[lane]), v1 = bf2f(hp[64 + lane]);
  float v2 = bf2f(hp[128 + lane]), v3 = bf2f(hp[192 + lane]);
  float ps0 = v0 * asw[lane],       pd0 = v0 * adw[lane];
  float ps1 = v1 * asw[64 + lane],  pd1 = v1 * adw[64 + lane];
  float ps2 = v2 * asw[128 + lane], pd2 = v2 * adw[128 + lane];
  float ps3 = v3 * asw[192 + lane], pd3 = v3 * adw[192 + lane];
  ps0 = wred_sum(ps0); ps1 = wred_sum(ps1); ps2 = wred_sum(ps2); ps3 = wred_sum(ps3);
  pd0 = wred_sum(pd0); pd1 = wred_sum(pd1); pd2 = wred_sum(pd2); pd3 = wred_sum(pd3);
  if (lane == 0) {
    asrc[wid * 4 + 0] = ps0; asrc[wid * 4 + 1] = ps1;
    asrc[wid * 4 + 2] = ps2; asrc[wid * 4 + 3] = ps3;
    adst[wid * 4 + 0] = pd0; adst[wid * 4 + 1] = pd1;
    adst[wid * 4 + 2] = pd2; adst[wid * 4 + 3] = pd3;
  }
}

// ------------ attention coefficients, layer 2 (C=40,H=4) ------------
__global__ __launch_bounds__(256) void k_att_l2(const u16* __restrict__ hb2,
                                                const float* __restrict__ asw,
                                                const float* __restrict__ adw,
                                                float* __restrict__ asrc,
                                                float* __restrict__ adst) {
  int wid = blockIdx.x * 4 + (threadIdx.x >> 6);
  int lane = threadIdx.x & 63;
  if (wid >= NNODES) return;
  const u16* hp = hb2 + (size_t)wid * 160;
  float ps0 = 0, ps1 = 0, ps2 = 0, ps3 = 0, pd0 = 0, pd1 = 0, pd2 = 0, pd3 = 0;
  if (lane < 40) {
    float v0 = bf2f(hp[lane]), v1 = bf2f(hp[40 + lane]);
    float v2 = bf2f(hp[80 + lane]), v3 = bf2f(hp[120 + lane]);
    ps0 = v0 * asw[lane];       pd0 = v0 * adw[lane];
    ps1 = v1 * asw[40 + lane];  pd1 = v1 * adw[40 + lane];
    ps2 = v2 * asw[80 + lane];  pd2 = v2 * adw[80 + lane];
    ps3 = v3 * asw[120 + lane]; pd3 = v3 * adw[120 + lane];
  }
  ps0 = wred_sum(ps0); ps1 = wred_sum(ps1); ps2 = wred_sum(ps2); ps3 = wred_sum(ps3);
  pd0 = wred_sum(pd0); pd1 = wred_sum(pd1); pd2 = wred_sum(pd2); pd3 = wred_sum(pd3);
  if (lane == 0) {
    asrc[wid * 4 + 0] = ps0; asrc[wid * 4 + 1] = ps1;
    asrc[wid * 4 + 2] = ps2; asrc[wid * 4 + 3] = ps3;
    adst[wid * 4 + 0] = pd0; adst[wid * 4 + 1] = pd1;
    adst[wid * 4 + 2] = pd2; adst[wid * 4 + 3] = pd3;
  }
}

// ---------- GAT aggregate, hidden layers: one wave per node ----------
__global__ __launch_bounds__(256) void k_aggr_hid(const u16* __restrict__ hb,
                                                  const float* __restrict__ asrc,
                                                  const float* __restrict__ adst,
                                                  const int* __restrict__ rowptr,
                                                  const int* __restrict__ colx,
                                                  const float* __restrict__ bias,
                                                  float* __restrict__ out) {
  int wid = blockIdx.x * 4 + (threadIdx.x >> 6);
  int lane = threadIdx.x & 63;
  if (wid >= NNODES) return;
  int beg = rowptr[wid], end = rowptr[wid + 1];
  float ad0 = adst[wid * 4 + 0], ad1 = adst[wid * 4 + 1];
  float ad2 = adst[wid * 4 + 2], ad3 = adst[wid * 4 + 3];

  // softmax denominators (shift-invariant: no max subtraction, logits ~ O(10))
  float s0 = 0.f, s1 = 0.f, s2 = 0.f, s3 = 0.f;
  for (int i = beg + lane; i < end; i += 64) {
    int s = colx[i];
    const float* ap = asrc + (size_t)s * 4;
    s0 += expf(lrelu(ap[0] + ad0, 0.2f));
    s1 += expf(lrelu(ap[1] + ad1, 0.2f));
    s2 += expf(lrelu(ap[2] + ad2, 0.2f));
    s3 += expf(lrelu(ap[3] + ad3, 0.2f));
  }
  s0 = wred_sum(s0); s1 = wred_sum(s1); s2 = wred_sum(s2); s3 = wred_sum(s3);

  int q = lane >> 4;  // head owning this lane's 4 channels
  float adq = (q == 0) ? ad0 : (q == 1) ? ad1 : (q == 2) ? ad2 : ad3;
  float sq  = (q == 0) ? s0  : (q == 1) ? s1  : (q == 2) ? s2  : s3;

  float ax = 0.f, ay = 0.f, az = 0.f, aw = 0.f;
  const u16* hbl = hb + lane * 4;
  int i = beg;
  for (; i + 4 <= end; i += 4) {
    int e0 = colx[i], e1 = colx[i + 1], e2 = colx[i + 2], e3 = colx[i + 3];
    float w0 = expf(lrelu(asrc[(size_t)e0 * 4 + q] + adq, 0.2f));
    float w1 = expf(lrelu(asrc[(size_t)e1 * 4 + q] + adq, 0.2f));
    float w2 = expf(lrelu(asrc[(size_t)e2 * 4 + q] + adq, 0.2f));
    float w3 = expf(lrelu(asrc[(size_t)e3 * 4 + q] + adq, 0.2f));
    ushort4 r0 = *(const ushort4*)(hbl + (size_t)e0 * 256);
    ushort4 r1 = *(const ushort4*)(hbl + (size_t)e1 * 256);
    ushort4 r2 = *(const ushort4*)(hbl + (size_t)e2 * 256);
    ushort4 r3 = *(const ushort4*)(hbl + (size_t)e3 * 256);
    ax = fmaf(w0, bf2f(r0.x), ax); ay = fmaf(w0, bf2f(r0.y), ay);
    az = fmaf(w0, bf2f(r0.z), az); aw = fmaf(w0, bf2f(r0.w), aw);
    ax = fmaf(w1, bf2f(r1.x), ax); ay = fmaf(w1, bf2f(r1.y), ay);
    az = fmaf(w1, bf2f(r1.z), az); aw = fmaf(w1, bf2f(r1.w), aw);
    ax = fmaf(w2, bf2f(r2.x), ax); ay = fmaf(w2, bf2f(r2.y), ay);
    az = fmaf(w2, bf2f(r2.z), az); aw = fmaf(w2, bf2f(r2.w), aw);
    ax = fmaf(w3, bf2f(r3.x), ax); ay = fmaf(w3, bf2f(r3.y), ay);
    az = fmaf(w3, bf2f(r3.z), az); aw = fmaf(w3, bf2f(r3.w), aw);
  }
  for (; i < end; ++i) {
    int e0 = colx[i];
    float w0 = expf(lrelu(asrc[(size_t)e0 * 4 + q] + adq, 0.2f));
    ushort4 r0 = *(const ushort4*)(hbl + (size_t)e0 * 256);
    ax = fmaf(w0, bf2f(r0.x), ax); ay = fmaf(w0, bf2f(r0.y), ay);
    az = fmaf(w0, bf2f(r0.z), az); aw = fmaf(w0, bf2f(r0.w), aw);
  }
  float inv = 1.f / (sq + 1e-16f);
  float4 b4 = ((const float4*)bias)[lane];
  float4 o = {fmaf(ax, inv, b4.x), fmaf(ay, inv, b4.y),
              fmaf(az, inv, b4.z), fmaf(aw, inv, b4.w)};
  ((float4*)out)[(size_t)wid * 64 + lane] = o;
}

// ---- layer-2 aggregate + head-mean + bias + log_softmax (fused) ----
__global__ __launch_bounds__(256) void k_aggr_l2(const u16* __restrict__ hb2,
                                                 const float* __restrict__ asrc,
                                                 const float* __restrict__ adst,
                                                 const int* __restrict__ rowptr,
                                                 const int* __restrict__ colx,
                                                 const float* __restrict__ b2,
                                                 float* __restrict__ out) {
  __shared__ float tile[4][160];
  int wv = threadIdx.x >> 6;
  int wid = blockIdx.x * 4 + wv;
  int lane = threadIdx.x & 63;
  bool valid = (wid < NNODES);
  int beg = 0, end = 0;
  float ad0 = 0, ad1 = 0, ad2 = 0, ad3 = 0;
  if (valid) {
    beg = rowptr[wid]; end = rowptr[wid + 1];
    ad0 = adst[wid * 4 + 0]; ad1 = adst[wid * 4 + 1];
    ad2 = adst[wid * 4 + 2]; ad3 = adst[wid * 4 + 3];
  }
  float s0 = 0.f, s1 = 0.f, s2 = 0.f, s3 = 0.f;
  for (int i = beg + lane; i < end; i += 64) {
    int s = colx[i];
    const float* ap = asrc + (size_t)s * 4;
    s0 += expf(lrelu(ap[0] + ad0, 0.2f));
    s1 += expf(lrelu(ap[1] + ad1, 0.2f));
    s2 += expf(lrelu(ap[2] + ad2, 0.2f));
    s3 += expf(lrelu(ap[3] + ad3, 0.2f));
  }
  s0 = wred_sum(s0); s1 = wred_sum(s1); s2 = wred_sum(s2); s3 = wred_sum(s3);

  int q = lane / 10; if (q > 3) q = 3;  // head for this lane's 4 channels (lanes<40)
  float adq = (q == 0) ? ad0 : (q == 1) ? ad1 : (q == 2) ? ad2 : ad3;
  float sq  = (q == 0) ? s0  : (q == 1) ? s1  : (q == 2) ? s2  : s3;

  float ax = 0.f, ay = 0.f, az = 0.f, aw = 0.f;
  const u16* hbl = hb2 + lane * 4;
  int i = beg;
  for (; i + 4 <= end; i += 4) {
    int e0 = colx[i], e1 = colx[i + 1], e2 = colx[i + 2], e3 = colx[i + 3];
    float w0 = expf(lrelu(asrc[(size_t)e0 * 4 + q] + adq, 0.2f));
    float w1 = expf(lrelu(asrc[(size_t)e1 * 4 + q] + adq, 0.2f));
    float w2 = expf(lrelu(asrc[(size_t)e2 * 4 + q] + adq, 0.2f));
    float w3 = expf(lrelu(asrc[(size_t)e3 * 4 + q] + adq, 0.2f));
    if (lane < 40) {
      ushort4 r0 = *(const ushort4*)(hbl + (size_t)e0 * 160);
      ushort4 r1 = *(const ushort4*)(hbl + (size_t)e1 * 160);
      ushort4 r2 = *(const ushort4*)(hbl + (size_t)e2 * 160);
      ushort4 r3 = *(const ushort4*)(hbl + (size_t)e3 * 160);
      ax = fmaf(w0, bf2f(r0.x), ax); ay = fmaf(w0, bf2f(r0.y), ay);
      az = fmaf(w0, bf2f(r0.z), az); aw = fmaf(w0, bf2f(r0.w), aw);
      ax = fmaf(w1, bf2f(r1.x), ax); ay = fmaf(w1, bf2f(r1.y), ay);
      az = fmaf(w1, bf2f(r1.z), az); aw = fmaf(w1, bf2f(r1.w), aw);
      ax = fmaf(w2, bf2f(r2.x), ax); ay = fmaf(w2, bf2f(r2.y), ay);
      az = fmaf(w2, bf2f(r2.z), az); aw = fmaf(w2, bf2f(r2.w), aw);
      ax = fmaf(w3, bf2f(r3.x), ax); ay = fmaf(w3, bf2f(r3.y), ay);
      az = fmaf(w3, bf2f(r3.z), az); aw = fmaf(w3, bf2f(r3.w), aw);
    }
  }
  for (; i < end; ++i) {
    int e0 = colx[i];
    float w0 = expf(lrelu(asrc[(size_t)e0 * 4 + q] + adq, 0.2f));
    if (lane < 40) {
      ushort4 r0 = *(const ushort4*)(hbl + (size_t)e0 * 160);
      ax = fmaf(w0, bf2f(r0.x), ax); ay = fmaf(w0, bf2f(r0.y), ay);
      az = fmaf(w0, bf2f(r0.z), az); aw = fmaf(w0, bf2f(r0.w), aw);
    }
  }
  if (valid && lane < 40) {
    float inv = 1.f / (sq + 1e-16f);
    tile[wv][lane * 4 + 0] = ax * inv;
    tile[wv][lane * 4 + 1] = ay * inv;
    tile[wv][lane * 4 + 2] = az * inv;
    tile[wv][lane * 4 + 3] = aw * inv;
  }
  __syncthreads();
  int c = lane;
  float val = -3.0e38f;
  if (valid && c < 40) {
    val = 0.25f * (tile[wv][c] + tile[wv][c + 40] + tile[wv][c + 80] + tile[wv][c + 120]) + b2[c];
  }
  float mv = (valid && c < 40) ? val : -3.0e38f;
  mv = wred_max(mv);
  float ex = (valid && c < 40) ? expf(val - mv) : 0.f;
  ex = wred_sum(ex);
  if (valid && c < 40) out[(size_t)wid * 40 + c] = val - mv - logf(ex);
}

// ---------------- batch norm ----------------
__global__ __launch_bounds__(256) void k_bnstats(const float* __restrict__ x,
                                                 float* __restrict__ stat) {
  int c = threadIdx.x;  // 256 channels
  const int rows = (NNODES + gridDim.x - 1) / gridDim.x;
  int r0 = blockIdx.x * rows;
  int r1 = min(NNODES, r0 + rows);
  float s = 0.f, qq = 0.f;
  for (int r = r0; r < r1; ++r) {
    float v = x[(size_t)r * 256 + c];
    s += v;
    qq = fmaf(v, v, qq);
  }
  atomicAdd(&stat[c], s);
  atomicAdd(&stat[256 + c], qq);
}

__global__ void k_bnfin(const float* __restrict__ stat, const float* __restrict__ g,
                        const float* __restrict__ be, float* __restrict__ sc,
                        float* __restrict__ sh) {
  int c = threadIdx.x;
  float mean = stat[c] * (1.0f / NNODES);
  float var = stat[256 + c] * (1.0f / NNODES) - mean * mean;
  float inv = rsqrtf(var + 1e-5f);
  float a = g[c] * inv;
  sc[c] = a;
  sh[c] = be[c] - mean * a;
}

__global__ void k_bnapply(float* __restrict__ x, const float* __restrict__ sc,
                          const float* __restrict__ sh) {
  int idx = blockIdx.x * blockDim.x + threadIdx.x;  // over N*64 float4s
  if (idx >= NNODES * 64) return;
  float4 v = ((float4*)x)[idx];
  int cb = (idx & 63) * 4;
  v.x = lrelu(fmaf(v.x, sc[cb + 0], sh[cb + 0]), 0.1f);
  v.y = lrelu(fmaf(v.y, sc[cb + 1], sh[cb + 1]), 0.1f);
  v.z = lrelu(fmaf(v.z, sc[cb + 2], sh[cb + 2]), 0.1f);
  v.w = lrelu(fmaf(v.w, sc[cb + 3], sh[cb + 3]), 0.1f);
  ((float4*)x)[idx] = v;
}

// ---------------- launch ----------------
extern "C" void kernel_launch(void* const* d_in, const int* in_sizes, int n_in,
                              void* d_out, int out_size, void* d_ws, size_t ws_size,
                              hipStream_t stream) {
  const float* x   = (const float*)d_in[0];
  const int*   adj = (const int*)d_in[1];
  const float* W0  = (const float*)d_in[2];
  const float* as0 = (const float*)d_in[3];
  const float* ad0 = (const float*)d_in[4];
  const float* b0  = (const float*)d_in[5];
  const float* W1  = (const float*)d_in[6];
  const float* as1 = (const float*)d_in[7];
  const float* ad1 = (const float*)d_in[8];
  const float* b1  = (const float*)d_in[9];
  const float* W2  = (const float*)d_in[10];
  const float* as2 = (const float*)d_in[11];
  const float* ad2 = (const float*)d_in[12];
  const float* b2  = (const float*)d_in[13];
  const float* g0  = (const float*)d_in[14];
  const float* be0 = (const float*)d_in[15];
  const float* g1  = (const float*)d_in[16];
  const float* be1 = (const float*)d_in[17];
  float* out = (float*)d_out;

  float* ws   = (float*)d_ws;
  float* bufA = ws;                                  // N*256 f32 (agg / post-BN)
  float* asrc = bufA + (size_t)NNODES * 256;         // N*4
  float* adst = asrc + (size_t)NNODES * 4;           // N*4
  float* stat = adst + (size_t)NNODES * 4;           // 512
  float* bnsc = stat + 512;                          // 256
  float* bnsh = bnsc + 256;                          // 256
  u16*   hb   = (u16*)(bnsh + 256);                  // N*256 bf16 (h payload)
  int* rowptr = (int*)(hb + (size_t)NNODES * 256);   // N+1
  int* fill   = rowptr + (NNODES + 1);               // N
  int* colx   = fill + NNODES;                       // EPTOT
  int* deg    = colx + EPTOT;                        // N
  int* part   = deg + NNODES;                        // N
  int* bsum   = part + NNODES;                       // SCAN_NB

  // CSR build (by destination), self-loops appended as edges E..E+N-1
  hipMemsetAsync(deg, 0, NNODES * sizeof(int), stream);
  k_hist<<<(EPTOT + 255) / 256, 256, 0, stream>>>(adj, deg);
  k_scan1<<<SCAN_NB, 256, 0, stream>>>(deg, part, bsum);
  k_scan2<<<1, 256, 0, stream>>>(bsum);
  k_scan3<<<SCAN_NB, 256, 0, stream>>>(part, bsum, rowptr, fill);
  k_fill<<<(EPTOT + 255) / 256, 256, 0, stream>>>(adj, fill, colx);

  dim3 gg((NNODES + 127) / 128, 2);

  // layer 0
  k_gemm<<<gg, 256, 0, stream>>>(x, W0, hb, NNODES, 128, 256);
  k_att_hid<<<12500, 256, 0, stream>>>(hb, as0, ad0, asrc, adst);
  k_aggr_hid<<<12500, 256, 0, stream>>>(hb, asrc, adst, rowptr, colx, b0, bufA);
  hipMemsetAsync(stat, 0, 512 * sizeof(float), stream);
  k_bnstats<<<400, 256, 0, stream>>>(bufA, stat);
  k_bnfin<<<1, 256, 0, stream>>>(stat, g0, be0, bnsc, bnsh);
  k_bnapply<<<12500, 256, 0, stream>>>(bufA, bnsc, bnsh);

  // layer 1
  k_gemm<<<gg, 256, 0, stream>>>(bufA, W1, hb, NNODES, 256, 256);
  k_att_hid<<<12500, 256, 0, stream>>>(hb, as1, ad1, asrc, adst);
  k_aggr_hid<<<12500, 256, 0, stream>>>(hb, asrc, adst, rowptr, colx, b1, bufA);
  hipMemsetAsync(stat, 0, 512 * sizeof(float), stream);
  k_bnstats<<<400, 256, 0, stream>>>(bufA, stat);
  k_bnfin<<<1, 256, 0, stream>>>(stat, g1, be1, bnsc, bnsh);
  k_bnapply<<<12500, 256, 0, stream>>>(bufA, bnsc, bnsh);

  // layer 2 (heads averaged) + fused log_softmax
  k_gemm<<<gg, 256, 0, stream>>>(bufA, W2, hb, NNODES, 256, 160);
  k_att_l2<<<12500, 256, 0, stream>>>(hb, as2, ad2, asrc, adst);
  k_aggr_l2<<<12500, 256, 0, stream>>>(hb, asrc, adst, rowptr, colx, b2, out);
}

// Round 4
// 591.418 us; speedup vs baseline: 1.7692x; 1.2871x over previous
//
#include <hip/hip_runtime.h>

#define NNODES 50000
#define NEDGES 800000
#define EPTOT  (NEDGES + NNODES)
#define SCAN_NB ((NNODES + 255) / 256)

typedef unsigned short u16;
typedef unsigned int   u32;
typedef __attribute__((ext_vector_type(8))) short s16x8;
typedef __attribute__((ext_vector_type(4))) float f32x4;

static __device__ __forceinline__ float lrelu(float x, float s) { return x > 0.f ? x : s * x; }
static __device__ __forceinline__ float bf2f(u16 b) { return __uint_as_float((u32)b << 16); }
static __device__ __forceinline__ u16 f2bf(float f) {
  u32 u = __float_as_uint(f);
  u32 r = (u + 0x7FFFu + ((u >> 16) & 1u)) >> 16;  // round-nearest-even
  return (u16)r;
}

__device__ __forceinline__ float wred_max(float v) {
#pragma unroll
  for (int off = 32; off; off >>= 1) v = fmaxf(v, __shfl_xor(v, off));
  return v;
}
__device__ __forceinline__ float wred_sum(float v) {
#pragma unroll
  for (int off = 32; off; off >>= 1) v += __shfl_xor(v, off);
  return v;
}

// ---------------- CSR build ----------------
__global__ void k_hist(const int* __restrict__ adj, int* __restrict__ deg) {
  int i = blockIdx.x * blockDim.x + threadIdx.x;
  if (i >= EPTOT) return;
  int d = (i < NEDGES) ? adj[NEDGES + i] : (i - NEDGES);
  atomicAdd(&deg[d], 1);
}

__global__ __launch_bounds__(256) void k_scan1(const int* __restrict__ deg,
                                               int* __restrict__ part,
                                               int* __restrict__ bsum) {
  __shared__ int sm[256];
  int t = threadIdx.x;
  int i = blockIdx.x * 256 + t;
  int v = (i < NNODES) ? deg[i] : 0;
  sm[t] = v;
  __syncthreads();
#pragma unroll
  for (int off = 1; off < 256; off <<= 1) {
    int u = (t >= off) ? sm[t - off] : 0;
    __syncthreads();
    sm[t] += u;
    __syncthreads();
  }
  if (i < NNODES) part[i] = sm[t] - v;
  if (t == 255) bsum[blockIdx.x] = sm[255];
}

__global__ __launch_bounds__(256) void k_scan2(int* __restrict__ bsum) {
  __shared__ int sm[256];
  int t = threadIdx.x;
  int v = (t < SCAN_NB) ? bsum[t] : 0;
  sm[t] = v;
  __syncthreads();
#pragma unroll
  for (int off = 1; off < 256; off <<= 1) {
    int u = (t >= off) ? sm[t - off] : 0;
    __syncthreads();
    sm[t] += u;
    __syncthreads();
  }
  if (t < SCAN_NB) bsum[t] = sm[t] - v;
}

__global__ __launch_bounds__(256) void k_scan3(const int* __restrict__ part,
                                               const int* __restrict__ bsum,
                                               int* __restrict__ rowptr,
                                               int* __restrict__ fill) {
  int i = blockIdx.x * 256 + threadIdx.x;
  if (i == 0) rowptr[NNODES] = EPTOT;
  if (i >= NNODES) return;
  int r = part[i] + bsum[blockIdx.x];
  rowptr[i] = r;
  fill[i] = r;
}

__global__ void k_fill(const int* __restrict__ adj, int* __restrict__ fill,
                       int* __restrict__ colx) {
  int i = blockIdx.x * blockDim.x + threadIdx.x;
  if (i >= EPTOT) return;
  int s, d;
  if (i < NEDGES) { s = adj[i]; d = adj[NEDGES + i]; }
  else            { s = i - NEDGES; d = s; }
  int pos = atomicAdd(&fill[d], 1);
  colx[pos] = s;
}

// ---- transpose+convert W[K,Nc](f32) -> Wt[Nc,K](bf16) ----
__global__ void k_wt(const float* __restrict__ W, u16* __restrict__ Wt, int K, int Nc) {
  int i = blockIdx.x * blockDim.x + threadIdx.x;
  if (i >= K * Nc) return;
  int n = i % Nc, k = i / Nc;  // coalesced read of W
  Wt[(size_t)n * K + k] = f2bf(W[i]);
}

// -------- MFMA GEMM: Cb[M,Nc](bf16) = A[M,K](f32) @ Wt[Nc,K](bf16)^T --------
// 128x128 tile, BK=32, 4 waves (2x2), each wave 64x64 via 4x4 16x16x32 frags.
__global__ __launch_bounds__(256) void k_gemm_mfma(const float* __restrict__ A,
                                                   const u16* __restrict__ Wt,
                                                   u16* __restrict__ Cb,
                                                   int M, int K, int Nc) {
  __shared__ u16 As[128 * 40];  // rows padded to 40 bf16 (80B) -> <=2-way bank alias
  __shared__ u16 Bs[128 * 40];
  const int tid = threadIdx.x;
  const int lane = tid & 63;
  const int wv = tid >> 6;
  const int wr = (wv >> 1) * 64, wc = (wv & 1) * 64;
  const int lr = lane & 15, lk = (lane >> 4) * 8;
  const int bm = blockIdx.x * 128, bn = blockIdx.y * 128;

  // staging assignment: 512 chunks of 8 elems; thread handles chunk tid, tid+256
  const int row0 = tid >> 2, kc0 = (tid & 3) * 8;
  const int ch1 = tid + 256;
  const int row1 = ch1 >> 2, kc1 = (ch1 & 3) * 8;

  f32x4 acc[4][4];
#pragma unroll
  for (int i = 0; i < 4; ++i)
#pragma unroll
    for (int j = 0; j < 4; ++j) {
      f32x4 z = {0.f, 0.f, 0.f, 0.f};
      acc[i][j] = z;
    }

  for (int k0 = 0; k0 < K; k0 += 32) {
    // ---- load to regs (A: f32 -> bf16 convert; B: bf16 direct) ----
    float4 a00 = {0,0,0,0}, a01 = {0,0,0,0}, a10 = {0,0,0,0}, a11 = {0,0,0,0};
    uint4 bv0 = {0,0,0,0}, bv1 = {0,0,0,0};
    {
      int ga = bm + row0;
      if (ga < M) {
        const float* p = A + (size_t)ga * K + k0 + kc0;
        a00 = *(const float4*)p; a01 = *(const float4*)(p + 4);
      }
      int gb = bn + row0;
      if (gb < Nc) bv0 = *(const uint4*)(Wt + (size_t)gb * K + k0 + kc0);
    }
    {
      int ga = bm + row1;
      if (ga < M) {
        const float* p = A + (size_t)ga * K + k0 + kc1;
        a10 = *(const float4*)p; a11 = *(const float4*)(p + 4);
      }
      int gb = bn + row1;
      if (gb < Nc) bv1 = *(const uint4*)(Wt + (size_t)gb * K + k0 + kc1);
    }
    ushort4 h00 = {f2bf(a00.x), f2bf(a00.y), f2bf(a00.z), f2bf(a00.w)};
    ushort4 h01 = {f2bf(a01.x), f2bf(a01.y), f2bf(a01.z), f2bf(a01.w)};
    ushort4 h10 = {f2bf(a10.x), f2bf(a10.y), f2bf(a10.z), f2bf(a10.w)};
    ushort4 h11 = {f2bf(a11.x), f2bf(a11.y), f2bf(a11.z), f2bf(a11.w)};

    __syncthreads();  // previous iter's compute done
    *(ushort4*)&As[row0 * 40 + kc0]     = h00;
    *(ushort4*)&As[row0 * 40 + kc0 + 4] = h01;
    *(ushort4*)&As[row1 * 40 + kc1]     = h10;
    *(ushort4*)&As[row1 * 40 + kc1 + 4] = h11;
    *(uint4*)&Bs[row0 * 40 + kc0] = bv0;
    *(uint4*)&Bs[row1 * 40 + kc1] = bv1;
    __syncthreads();

    s16x8 af[4], bf[4];
#pragma unroll
    for (int mi = 0; mi < 4; ++mi)
      af[mi] = *(const s16x8*)&As[(wr + mi * 16 + lr) * 40 + lk];
#pragma unroll
    for (int ni = 0; ni < 4; ++ni)
      bf[ni] = *(const s16x8*)&Bs[(wc + ni * 16 + lr) * 40 + lk];
#pragma unroll
    for (int mi = 0; mi < 4; ++mi)
#pragma unroll
      for (int ni = 0; ni < 4; ++ni)
        acc[mi][ni] = __builtin_amdgcn_mfma_f32_16x16x32_bf16(af[mi], bf[ni], acc[mi][ni], 0, 0, 0);
  }

  // epilogue: D col = lane&15, row = (lane>>4)*4 + reg
#pragma unroll
  for (int mi = 0; mi < 4; ++mi) {
    int rowb = bm + wr + mi * 16 + (lane >> 4) * 4;
#pragma unroll
    for (int ni = 0; ni < 4; ++ni) {
      int col = bn + wc + ni * 16 + lr;
      if (col >= Nc) continue;
#pragma unroll
      for (int r = 0; r < 4; ++r) {
        int row = rowb + r;
        if (row < M) Cb[(size_t)row * Nc + col] = f2bf(acc[mi][ni][r]);
      }
    }
  }
}

// ------------ attention coefficients, hidden layers (C=64,H=4) ------------
__global__ __launch_bounds__(256) void k_att_hid(const u16* __restrict__ hb,
                                                 const float* __restrict__ asw,
                                                 const float* __restrict__ adw,
                                                 float* __restrict__ asrc,
                                                 float* __restrict__ adst) {
  int wid = blockIdx.x * 4 + (threadIdx.x >> 6);
  int lane = threadIdx.x & 63;
  if (wid >= NNODES) return;
  const u16* hp = hb + (size_t)wid * 256;
  float v0 = bf2f(hp[lane]), v1 = bf2f(hp[64 + lane]);
  float v2 = bf2f(hp[128 + lane]), v3 = bf2f(hp[192 + lane]);
  float ps0 = v0 * asw[lane],       pd0 = v0 * adw[lane];
  float ps1 = v1 * asw[64 + lane],  pd1 = v1 * adw[64 + lane];
  float ps2 = v2 * asw[128 + lane], pd2 = v2 * adw[128 + lane];
  float ps3 = v3 * asw[192 + lane], pd3 = v3 * adw[192 + lane];
  ps0 = wred_sum(ps0); ps1 = wred_sum(ps1); ps2 = wred_sum(ps2); ps3 = wred_sum(ps3);
  pd0 = wred_sum(pd0); pd1 = wred_sum(pd1); pd2 = wred_sum(pd2); pd3 = wred_sum(pd3);
  if (lane == 0) {
    asrc[wid * 4 + 0] = ps0; asrc[wid * 4 + 1] = ps1;
    asrc[wid * 4 + 2] = ps2; asrc[wid * 4 + 3] = ps3;
    adst[wid * 4 + 0] = pd0; adst[wid * 4 + 1] = pd1;
    adst[wid * 4 + 2] = pd2; adst[wid * 4 + 3] = pd3;
  }
}

// ------------ attention coefficients, layer 2 (C=40,H=4) ------------
__global__ __launch_bounds__(256) void k_att_l2(const u16* __restrict__ hb2,
                                                const float* __restrict__ asw,
                                                const float* __restrict__ adw,
                                                float* __restrict__ asrc,
                                                float* __restrict__ adst) {
  int wid = blockIdx.x * 4 + (threadIdx.x >> 6);
  int lane = threadIdx.x & 63;
  if (wid >= NNODES) return;
  const u16* hp = hb2 + (size_t)wid * 160;
  float ps0 = 0, ps1 = 0, ps2 = 0, ps3 = 0, pd0 = 0, pd1 = 0, pd2 = 0, pd3 = 0;
  if (lane < 40) {
    float v0 = bf2f(hp[lane]), v1 = bf2f(hp[40 + lane]);
    float v2 = bf2f(hp[80 + lane]), v3 = bf2f(hp[120 + lane]);
    ps0 = v0 * asw[lane];       pd0 = v0 * adw[lane];
    ps1 = v1 * asw[40 + lane];  pd1 = v1 * adw[40 + lane];
    ps2 = v2 * asw[80 + lane];  pd2 = v2 * adw[80 + lane];
    ps3 = v3 * asw[120 + lane]; pd3 = v3 * adw[120 + lane];
  }
  ps0 = wred_sum(ps0); ps1 = wred_sum(ps1); ps2 = wred_sum(ps2); ps3 = wred_sum(ps3);
  pd0 = wred_sum(pd0); pd1 = wred_sum(pd1); pd2 = wred_sum(pd2); pd3 = wred_sum(pd3);
  if (lane == 0) {
    asrc[wid * 4 + 0] = ps0; asrc[wid * 4 + 1] = ps1;
    asrc[wid * 4 + 2] = ps2; asrc[wid * 4 + 3] = ps3;
    adst[wid * 4 + 0] = pd0; adst[wid * 4 + 1] = pd1;
    adst[wid * 4 + 2] = pd2; adst[wid * 4 + 3] = pd3;
  }
}

// ---------- GAT aggregate, hidden layers: one wave per node ----------
__global__ __launch_bounds__(256) void k_aggr_hid(const u16* __restrict__ hb,
                                                  const float* __restrict__ asrc,
                                                  const float* __restrict__ adst,
                                                  const int* __restrict__ rowptr,
                                                  const int* __restrict__ colx,
                                                  const float* __restrict__ bias,
                                                  float* __restrict__ out) {
  int wid = blockIdx.x * 4 + (threadIdx.x >> 6);
  int lane = threadIdx.x & 63;
  if (wid >= NNODES) return;
  int beg = rowptr[wid], end = rowptr[wid + 1];
  float ad0 = adst[wid * 4 + 0], ad1 = adst[wid * 4 + 1];
  float ad2 = adst[wid * 4 + 2], ad3 = adst[wid * 4 + 3];

  float s0 = 0.f, s1 = 0.f, s2 = 0.f, s3 = 0.f;
  for (int i = beg + lane; i < end; i += 64) {
    int s = colx[i];
    const float* ap = asrc + (size_t)s * 4;
    s0 += expf(lrelu(ap[0] + ad0, 0.2f));
    s1 += expf(lrelu(ap[1] + ad1, 0.2f));
    s2 += expf(lrelu(ap[2] + ad2, 0.2f));
    s3 += expf(lrelu(ap[3] + ad3, 0.2f));
  }
  s0 = wred_sum(s0); s1 = wred_sum(s1); s2 = wred_sum(s2); s3 = wred_sum(s3);

  int q = lane >> 4;
  float adq = (q == 0) ? ad0 : (q == 1) ? ad1 : (q == 2) ? ad2 : ad3;
  float sq  = (q == 0) ? s0  : (q == 1) ? s1  : (q == 2) ? s2  : s3;

  float ax = 0.f, ay = 0.f, az = 0.f, aw = 0.f;
  const u16* hbl = hb + lane * 4;
  int i = beg;
  for (; i + 4 <= end; i += 4) {
    int e0 = colx[i], e1 = colx[i + 1], e2 = colx[i + 2], e3 = colx[i + 3];
    float w0 = expf(lrelu(asrc[(size_t)e0 * 4 + q] + adq, 0.2f));
    float w1 = expf(lrelu(asrc[(size_t)e1 * 4 + q] + adq, 0.2f));
    float w2 = expf(lrelu(asrc[(size_t)e2 * 4 + q] + adq, 0.2f));
    float w3 = expf(lrelu(asrc[(size_t)e3 * 4 + q] + adq, 0.2f));
    ushort4 r0 = *(const ushort4*)(hbl + (size_t)e0 * 256);
    ushort4 r1 = *(const ushort4*)(hbl + (size_t)e1 * 256);
    ushort4 r2 = *(const ushort4*)(hbl + (size_t)e2 * 256);
    ushort4 r3 = *(const ushort4*)(hbl + (size_t)e3 * 256);
    ax = fmaf(w0, bf2f(r0.x), ax); ay = fmaf(w0, bf2f(r0.y), ay);
    az = fmaf(w0, bf2f(r0.z), az); aw = fmaf(w0, bf2f(r0.w), aw);
    ax = fmaf(w1, bf2f(r1.x), ax); ay = fmaf(w1, bf2f(r1.y), ay);
    az = fmaf(w1, bf2f(r1.z), az); aw = fmaf(w1, bf2f(r1.w), aw);
    ax = fmaf(w2, bf2f(r2.x), ax); ay = fmaf(w2, bf2f(r2.y), ay);
    az = fmaf(w2, bf2f(r2.z), az); aw = fmaf(w2, bf2f(r2.w), aw);
    ax = fmaf(w3, bf2f(r3.x), ax); ay = fmaf(w3, bf2f(r3.y), ay);
    az = fmaf(w3, bf2f(r3.z), az); aw = fmaf(w3, bf2f(r3.w), aw);
  }
  for (; i < end; ++i) {
    int e0 = colx[i];
    float w0 = expf(lrelu(asrc[(size_t)e0 * 4 + q] + adq, 0.2f));
    ushort4 r0 = *(const ushort4*)(hbl + (size_t)e0 * 256);
    ax = fmaf(w0, bf2f(r0.x), ax); ay = fmaf(w0, bf2f(r0.y), ay);
    az = fmaf(w0, bf2f(r0.z), az); aw = fmaf(w0, bf2f(r0.w), aw);
  }
  float inv = 1.f / (sq + 1e-16f);
  float4 b4 = ((const float4*)bias)[lane];
  float4 o = {fmaf(ax, inv, b4.x), fmaf(ay, inv, b4.y),
              fmaf(az, inv, b4.z), fmaf(aw, inv, b4.w)};
  ((float4*)out)[(size_t)wid * 64 + lane] = o;
}

// ---- layer-2 aggregate + head-mean + bias + log_softmax (fused) ----
__global__ __launch_bounds__(256) void k_aggr_l2(const u16* __restrict__ hb2,
                                                 const float* __restrict__ asrc,
                                                 const float* __restrict__ adst,
                                                 const int* __restrict__ rowptr,
                                                 const int* __restrict__ colx,
                                                 const float* __restrict__ b2,
                                                 float* __restrict__ out) {
  __shared__ float tile[4][160];
  int wv = threadIdx.x >> 6;
  int wid = blockIdx.x * 4 + wv;
  int lane = threadIdx.x & 63;
  bool valid = (wid < NNODES);
  int beg = 0, end = 0;
  float ad0 = 0, ad1 = 0, ad2 = 0, ad3 = 0;
  if (valid) {
    beg = rowptr[wid]; end = rowptr[wid + 1];
    ad0 = adst[wid * 4 + 0]; ad1 = adst[wid * 4 + 1];
    ad2 = adst[wid * 4 + 2]; ad3 = adst[wid * 4 + 3];
  }
  float s0 = 0.f, s1 = 0.f, s2 = 0.f, s3 = 0.f;
  for (int i = beg + lane; i < end; i += 64) {
    int s = colx[i];
    const float* ap = asrc + (size_t)s * 4;
    s0 += expf(lrelu(ap[0] + ad0, 0.2f));
    s1 += expf(lrelu(ap[1] + ad1, 0.2f));
    s2 += expf(lrelu(ap[2] + ad2, 0.2f));
    s3 += expf(lrelu(ap[3] + ad3, 0.2f));
  }
  s0 = wred_sum(s0); s1 = wred_sum(s1); s2 = wred_sum(s2); s3 = wred_sum(s3);

  int q = lane / 10; if (q > 3) q = 3;
  float adq = (q == 0) ? ad0 : (q == 1) ? ad1 : (q == 2) ? ad2 : ad3;
  float sq  = (q == 0) ? s0  : (q == 1) ? s1  : (q == 2) ? s2  : s3;

  float ax = 0.f, ay = 0.f, az = 0.f, aw = 0.f;
  const u16* hbl = hb2 + lane * 4;
  int i = beg;
  for (; i + 4 <= end; i += 4) {
    int e0 = colx[i], e1 = colx[i + 1], e2 = colx[i + 2], e3 = colx[i + 3];
    float w0 = expf(lrelu(asrc[(size_t)e0 * 4 + q] + adq, 0.2f));
    float w1 = expf(lrelu(asrc[(size_t)e1 * 4 + q] + adq, 0.2f));
    float w2 = expf(lrelu(asrc[(size_t)e2 * 4 + q] + adq, 0.2f));
    float w3 = expf(lrelu(asrc[(size_t)e3 * 4 + q] + adq, 0.2f));
    if (lane < 40) {
      ushort4 r0 = *(const ushort4*)(hbl + (size_t)e0 * 160);
      ushort4 r1 = *(const ushort4*)(hbl + (size_t)e1 * 160);
      ushort4 r2 = *(const ushort4*)(hbl + (size_t)e2 * 160);
      ushort4 r3 = *(const ushort4*)(hbl + (size_t)e3 * 160);
      ax = fmaf(w0, bf2f(r0.x), ax); ay = fmaf(w0, bf2f(r0.y), ay);
      az = fmaf(w0, bf2f(r0.z), az); aw = fmaf(w0, bf2f(r0.w), aw);
      ax = fmaf(w1, bf2f(r1.x), ax); ay = fmaf(w1, bf2f(r1.y), ay);
      az = fmaf(w1, bf2f(r1.z), az); aw = fmaf(w1, bf2f(r1.w), aw);
      ax = fmaf(w2, bf2f(r2.x), ax); ay = fmaf(w2, bf2f(r2.y), ay);
      az = fmaf(w2, bf2f(r2.z), az); aw = fmaf(w2, bf2f(r2.w), aw);
      ax = fmaf(w3, bf2f(r3.x), ax); ay = fmaf(w3, bf2f(r3.y), ay);
      az = fmaf(w3, bf2f(r3.z), az); aw = fmaf(w3, bf2f(r3.w), aw);
    }
  }
  for (; i < end; ++i) {
    int e0 = colx[i];
    float w0 = expf(lrelu(asrc[(size_t)e0 * 4 + q] + adq, 0.2f));
    if (lane < 40) {
      ushort4 r0 = *(const ushort4*)(hbl + (size_t)e0 * 160);
      ax = fmaf(w0, bf2f(r0.x), ax); ay = fmaf(w0, bf2f(r0.y), ay);
      az = fmaf(w0, bf2f(r0.z), az); aw = fmaf(w0, bf2f(r0.w), aw);
    }
  }
  if (valid && lane < 40) {
    float inv = 1.f / (sq + 1e-16f);
    tile[wv][lane * 4 + 0] = ax * inv;
    tile[wv][lane * 4 + 1] = ay * inv;
    tile[wv][lane * 4 + 2] = az * inv;
    tile[wv][lane * 4 + 3] = aw * inv;
  }
  __syncthreads();
  int c = lane;
  float val = -3.0e38f;
  if (valid && c < 40) {
    val = 0.25f * (tile[wv][c] + tile[wv][c + 40] + tile[wv][c + 80] + tile[wv][c + 120]) + b2[c];
  }
  float mv = (valid && c < 40) ? val : -3.0e38f;
  mv = wred_max(mv);
  float ex = (valid && c < 40) ? expf(val - mv) : 0.f;
  ex = wred_sum(ex);
  if (valid && c < 40) out[(size_t)wid * 40 + c] = val - mv - logf(ex);
}

// ---------------- batch norm ----------------
__global__ __launch_bounds__(256) void k_bnstats(const float* __restrict__ x,
                                                 float* __restrict__ stat) {
  int c = threadIdx.x;
  const int rows = (NNODES + gridDim.x - 1) / gridDim.x;
  int r0 = blockIdx.x * rows;
  int r1 = min(NNODES, r0 + rows);
  float s = 0.f, qq = 0.f;
  for (int r = r0; r < r1; ++r) {
    float v = x[(size_t)r * 256 + c];
    s += v;
    qq = fmaf(v, v, qq);
  }
  atomicAdd(&stat[c], s);
  atomicAdd(&stat[256 + c], qq);
}

__global__ void k_bnfin(const float* __restrict__ stat, const float* __restrict__ g,
                        const float* __restrict__ be, float* __restrict__ sc,
                        float* __restrict__ sh) {
  int c = threadIdx.x;
  float mean = stat[c] * (1.0f / NNODES);
  float var = stat[256 + c] * (1.0f / NNODES) - mean * mean;
  float inv = rsqrtf(var + 1e-5f);
  float a = g[c] * inv;
  sc[c] = a;
  sh[c] = be[c] - mean * a;
}

__global__ void k_bnapply(float* __restrict__ x, const float* __restrict__ sc,
                          const float* __restrict__ sh) {
  int idx = blockIdx.x * blockDim.x + threadIdx.x;
  if (idx >= NNODES * 64) return;
  float4 v = ((float4*)x)[idx];
  int cb = (idx & 63) * 4;
  v.x = lrelu(fmaf(v.x, sc[cb + 0], sh[cb + 0]), 0.1f);
  v.y = lrelu(fmaf(v.y, sc[cb + 1], sh[cb + 1]), 0.1f);
  v.z = lrelu(fmaf(v.z, sc[cb + 2], sh[cb + 2]), 0.1f);
  v.w = lrelu(fmaf(v.w, sc[cb + 3], sh[cb + 3]), 0.1f);
  ((float4*)x)[idx] = v;
}

// ---------------- launch ----------------
extern "C" void kernel_launch(void* const* d_in, const int* in_sizes, int n_in,
                              void* d_out, int out_size, void* d_ws, size_t ws_size,
                              hipStream_t stream) {
  const float* x   = (const float*)d_in[0];
  const int*   adj = (const int*)d_in[1];
  const float* W0  = (const float*)d_in[2];
  const float* as0 = (const float*)d_in[3];
  const float* ad0 = (const float*)d_in[4];
  const float* b0  = (const float*)d_in[5];
  const float* W1  = (const float*)d_in[6];
  const float* as1 = (const float*)d_in[7];
  const float* ad1 = (const float*)d_in[8];
  const float* b1  = (const float*)d_in[9];
  const float* W2  = (const float*)d_in[10];
  const float* as2 = (const float*)d_in[11];
  const float* ad2 = (const float*)d_in[12];
  const float* b2  = (const float*)d_in[13];
  const float* g0  = (const float*)d_in[14];
  const float* be0 = (const float*)d_in[15];
  const float* g1  = (const float*)d_in[16];
  const float* be1 = (const float*)d_in[17];
  float* out = (float*)d_out;

  float* ws   = (float*)d_ws;
  float* bufA = ws;                                  // N*256 f32 (agg / post-BN)
  float* asrc = bufA + (size_t)NNODES * 256;         // N*4
  float* adst = asrc + (size_t)NNODES * 4;           // N*4
  float* stat = adst + (size_t)NNODES * 4;           // 512
  float* bnsc = stat + 512;                          // 256
  float* bnsh = bnsc + 256;                          // 256
  u16*   hb   = (u16*)(bnsh + 256);                  // N*256 bf16 (h payload)
  u16*   w0t  = hb + (size_t)NNODES * 256;           // 256*128 bf16 (W0^T)
  u16*   w1t  = w0t + 256 * 128;                     // 256*256 bf16 (W1^T)
  u16*   w2t  = w1t + 256 * 256;                     // 160*256 bf16 (W2^T)
  int* rowptr = (int*)(w2t + 160 * 256);             // N+1
  int* fill   = rowptr + (NNODES + 1);               // N
  int* colx   = fill + NNODES;                       // EPTOT
  int* deg    = colx + EPTOT;                        // N
  int* part   = deg + NNODES;                        // N
  int* bsum   = part + NNODES;                       // SCAN_NB

  // CSR build (by destination), self-loops appended as edges E..E+N-1
  hipMemsetAsync(deg, 0, NNODES * sizeof(int), stream);
  k_hist<<<(EPTOT + 255) / 256, 256, 0, stream>>>(adj, deg);
  k_scan1<<<SCAN_NB, 256, 0, stream>>>(deg, part, bsum);
  k_scan2<<<1, 256, 0, stream>>>(bsum);
  k_scan3<<<SCAN_NB, 256, 0, stream>>>(part, bsum, rowptr, fill);
  k_fill<<<(EPTOT + 255) / 256, 256, 0, stream>>>(adj, fill, colx);

  // weight transpose+convert (tiny)
  k_wt<<<(128 * 256 + 255) / 256, 256, 0, stream>>>(W0, w0t, 128, 256);
  k_wt<<<(256 * 256 + 255) / 256, 256, 0, stream>>>(W1, w1t, 256, 256);
  k_wt<<<(256 * 160 + 255) / 256, 256, 0, stream>>>(W2, w2t, 256, 160);

  dim3 gg2((NNODES + 127) / 128, 2);

  // layer 0 (K=128)
  k_gemm_mfma<<<gg2, 256, 0, stream>>>(x, w0t, hb, NNODES, 128, 256);
  k_att_hid<<<12500, 256, 0, stream>>>(hb, as0, ad0, asrc, adst);
  k_aggr_hid<<<12500, 256, 0, stream>>>(hb, asrc, adst, rowptr, colx, b0, bufA);
  hipMemsetAsync(stat, 0, 512 * sizeof(float), stream);
  k_bnstats<<<400, 256, 0, stream>>>(bufA, stat);
  k_bnfin<<<1, 256, 0, stream>>>(stat, g0, be0, bnsc, bnsh);
  k_bnapply<<<12500, 256, 0, stream>>>(bufA, bnsc, bnsh);

  // layer 1 (K=256)
  k_gemm_mfma<<<gg2, 256, 0, stream>>>(bufA, w1t, hb, NNODES, 256, 256);
  k_att_hid<<<12500, 256, 0, stream>>>(hb, as1, ad1, asrc, adst);
  k_aggr_hid<<<12500, 256, 0, stream>>>(hb, asrc, adst, rowptr, colx, b1, bufA);
  hipMemsetAsync(stat, 0, 512 * sizeof(float), stream);
  k_bnstats<<<400, 256, 0, stream>>>(bufA, stat);
  k_bnfin<<<1, 256, 0, stream>>>(stat, g1, be1, bnsc, bnsh);
  k_bnapply<<<12500, 256, 0, stream>>>(bufA, bnsc, bnsh);

  // layer 2 (K=256, Nc=160) + fused log_softmax
  k_gemm_mfma<<<gg2, 256, 0, stream>>>(bufA, w2t, hb, NNODES, 256, 160);
  k_att_l2<<<12500, 256, 0, stream>>>(hb, as2, ad2, asrc, adst);
  k_aggr_l2<<<12500, 256, 0, stream>>>(hb, asrc, adst, rowptr, colx, b2, out);
}

// Round 5
// 575.139 us; speedup vs baseline: 1.8192x; 1.0283x over previous
//
#include <hip/hip_runtime.h>

#define NNODES 50000
#define NEDGES 800000
#define EPTOT  (NEDGES + NNODES)
#define SCAN_NB ((NNODES + 255) / 256)

typedef unsigned short u16;
typedef unsigned int   u32;
typedef __attribute__((ext_vector_type(8))) short s16x8;
typedef __attribute__((ext_vector_type(4))) float f32x4;

static __device__ __forceinline__ float lrelu(float x, float s) { return x > 0.f ? x : s * x; }
static __device__ __forceinline__ float bf2f(u16 b) { return __uint_as_float((u32)b << 16); }
static __device__ __forceinline__ u16 f2bf(float f) {
  u32 u = __float_as_uint(f);
  u32 r = (u + 0x7FFFu + ((u >> 16) & 1u)) >> 16;  // round-nearest-even
  return (u16)r;
}

__device__ __forceinline__ float wred_max(float v) {
#pragma unroll
  for (int off = 32; off; off >>= 1) v = fmaxf(v, __shfl_xor(v, off));
  return v;
}
__device__ __forceinline__ float wred_sum(float v) {
#pragma unroll
  for (int off = 32; off; off >>= 1) v += __shfl_xor(v, off);
  return v;
}

// ---------------- CSR build ----------------
__global__ void k_hist(const int* __restrict__ adj, int* __restrict__ deg) {
  int i = blockIdx.x * blockDim.x + threadIdx.x;
  if (i >= EPTOT) return;
  int d = (i < NEDGES) ? adj[NEDGES + i] : (i - NEDGES);
  atomicAdd(&deg[d], 1);
}

__global__ __launch_bounds__(256) void k_scan1(const int* __restrict__ deg,
                                               int* __restrict__ part,
                                               int* __restrict__ bsum) {
  __shared__ int sm[256];
  int t = threadIdx.x;
  int i = blockIdx.x * 256 + t;
  int v = (i < NNODES) ? deg[i] : 0;
  sm[t] = v;
  __syncthreads();
#pragma unroll
  for (int off = 1; off < 256; off <<= 1) {
    int u = (t >= off) ? sm[t - off] : 0;
    __syncthreads();
    sm[t] += u;
    __syncthreads();
  }
  if (i < NNODES) part[i] = sm[t] - v;
  if (t == 255) bsum[blockIdx.x] = sm[255];
}

__global__ __launch_bounds__(256) void k_scan2(int* __restrict__ bsum) {
  __shared__ int sm[256];
  int t = threadIdx.x;
  int v = (t < SCAN_NB) ? bsum[t] : 0;
  sm[t] = v;
  __syncthreads();
#pragma unroll
  for (int off = 1; off < 256; off <<= 1) {
    int u = (t >= off) ? sm[t - off] : 0;
    __syncthreads();
    sm[t] += u;
    __syncthreads();
  }
  if (t < SCAN_NB) bsum[t] = sm[t] - v;
}

__global__ __launch_bounds__(256) void k_scan3(const int* __restrict__ part,
                                               const int* __restrict__ bsum,
                                               int* __restrict__ rowptr,
                                               int* __restrict__ fill) {
  int i = blockIdx.x * 256 + threadIdx.x;
  if (i == 0) rowptr[NNODES] = EPTOT;
  if (i >= NNODES) return;
  int r = part[i] + bsum[blockIdx.x];
  rowptr[i] = r;
  fill[i] = r;
}

__global__ void k_fill(const int* __restrict__ adj, int* __restrict__ fill,
                       int* __restrict__ colx) {
  int i = blockIdx.x * blockDim.x + threadIdx.x;
  if (i >= EPTOT) return;
  int s, d;
  if (i < NEDGES) { s = adj[i]; d = adj[NEDGES + i]; }
  else            { s = i - NEDGES; d = s; }
  int pos = atomicAdd(&fill[d], 1);
  colx[pos] = s;
}

// ---- transpose+convert W[K,Nc](f32) -> Wt[Nc,K](bf16) ----
__global__ void k_wt(const float* __restrict__ W, u16* __restrict__ Wt, int K, int Nc) {
  int i = blockIdx.x * blockDim.x + threadIdx.x;
  if (i >= K * Nc) return;
  int n = i % Nc, k = i / Nc;
  Wt[(size_t)n * K + k] = f2bf(W[i]);
}

// -------- MFMA GEMM: Cb[M,Nc](bf16) = act(A[M,K]) @ Wt[Nc,K](bf16)^T --------
// If sc != null, A is pre-transformed elementwise: lrelu(a*sc[k]+sh[k], 0.1)
// (fused BN-apply + activation). 128x128 tile, BK=32, 4 waves 2x2, 4x4 frags.
__global__ __launch_bounds__(256) void k_gemm_mfma(const float* __restrict__ A,
                                                   const u16* __restrict__ Wt,
                                                   u16* __restrict__ Cb,
                                                   const float* __restrict__ sc,
                                                   const float* __restrict__ sh,
                                                   int M, int K, int Nc) {
  __shared__ u16 As[128 * 40];  // rows padded to 40 bf16 (80B) -> <=2-way bank alias
  __shared__ u16 Bs[128 * 40];
  const int tid = threadIdx.x;
  const int lane = tid & 63;
  const int wv = tid >> 6;
  const int wr = (wv >> 1) * 64, wc = (wv & 1) * 64;
  const int lr = lane & 15, lk = (lane >> 4) * 8;
  const int bm = blockIdx.x * 128, bn = blockIdx.y * 128;

  const int row0 = tid >> 2, kc0 = (tid & 3) * 8;
  const int ch1 = tid + 256;
  const int row1 = ch1 >> 2, kc1 = (ch1 & 3) * 8;

  f32x4 acc[4][4];
#pragma unroll
  for (int i = 0; i < 4; ++i)
#pragma unroll
    for (int j = 0; j < 4; ++j) {
      f32x4 z = {0.f, 0.f, 0.f, 0.f};
      acc[i][j] = z;
    }

  for (int k0 = 0; k0 < K; k0 += 32) {
    float4 a00 = {0,0,0,0}, a01 = {0,0,0,0}, a10 = {0,0,0,0}, a11 = {0,0,0,0};
    uint4 bv0 = {0,0,0,0}, bv1 = {0,0,0,0};
    {
      int ga = bm + row0;
      if (ga < M) {
        const float* p = A + (size_t)ga * K + k0 + kc0;
        a00 = *(const float4*)p; a01 = *(const float4*)(p + 4);
      }
      int gb = bn + row0;
      if (gb < Nc) bv0 = *(const uint4*)(Wt + (size_t)gb * K + k0 + kc0);
    }
    {
      int ga = bm + row1;
      if (ga < M) {
        const float* p = A + (size_t)ga * K + k0 + kc1;
        a10 = *(const float4*)p; a11 = *(const float4*)(p + 4);
      }
      int gb = bn + row1;
      if (gb < Nc) bv1 = *(const uint4*)(Wt + (size_t)gb * K + k0 + kc1);
    }
    if (sc) {  // fused BN+LeakyReLU(0.1) on A (garbage only in rows >= M, never stored)
      const float* s0p = sc + k0 + kc0; const float* h0p = sh + k0 + kc0;
      a00.x = lrelu(fmaf(a00.x, s0p[0], h0p[0]), 0.1f);
      a00.y = lrelu(fmaf(a00.y, s0p[1], h0p[1]), 0.1f);
      a00.z = lrelu(fmaf(a00.z, s0p[2], h0p[2]), 0.1f);
      a00.w = lrelu(fmaf(a00.w, s0p[3], h0p[3]), 0.1f);
      a01.x = lrelu(fmaf(a01.x, s0p[4], h0p[4]), 0.1f);
      a01.y = lrelu(fmaf(a01.y, s0p[5], h0p[5]), 0.1f);
      a01.z = lrelu(fmaf(a01.z, s0p[6], h0p[6]), 0.1f);
      a01.w = lrelu(fmaf(a01.w, s0p[7], h0p[7]), 0.1f);
      const float* s1p = sc + k0 + kc1; const float* h1p = sh + k0 + kc1;
      a10.x = lrelu(fmaf(a10.x, s1p[0], h1p[0]), 0.1f);
      a10.y = lrelu(fmaf(a10.y, s1p[1], h1p[1]), 0.1f);
      a10.z = lrelu(fmaf(a10.z, s1p[2], h1p[2]), 0.1f);
      a10.w = lrelu(fmaf(a10.w, s1p[3], h1p[3]), 0.1f);
      a11.x = lrelu(fmaf(a11.x, s1p[4], h1p[4]), 0.1f);
      a11.y = lrelu(fmaf(a11.y, s1p[5], h1p[5]), 0.1f);
      a11.z = lrelu(fmaf(a11.z, s1p[6], h1p[6]), 0.1f);
      a11.w = lrelu(fmaf(a11.w, s1p[7], h1p[7]), 0.1f);
    }
    ushort4 h00 = {f2bf(a00.x), f2bf(a00.y), f2bf(a00.z), f2bf(a00.w)};
    ushort4 h01 = {f2bf(a01.x), f2bf(a01.y), f2bf(a01.z), f2bf(a01.w)};
    ushort4 h10 = {f2bf(a10.x), f2bf(a10.y), f2bf(a10.z), f2bf(a10.w)};
    ushort4 h11 = {f2bf(a11.x), f2bf(a11.y), f2bf(a11.z), f2bf(a11.w)};

    __syncthreads();
    *(ushort4*)&As[row0 * 40 + kc0]     = h00;
    *(ushort4*)&As[row0 * 40 + kc0 + 4] = h01;
    *(ushort4*)&As[row1 * 40 + kc1]     = h10;
    *(ushort4*)&As[row1 * 40 + kc1 + 4] = h11;
    *(uint4*)&Bs[row0 * 40 + kc0] = bv0;
    *(uint4*)&Bs[row1 * 40 + kc1] = bv1;
    __syncthreads();

    s16x8 af[4], bfm[4];
#pragma unroll
    for (int mi = 0; mi < 4; ++mi)
      af[mi] = *(const s16x8*)&As[(wr + mi * 16 + lr) * 40 + lk];
#pragma unroll
    for (int ni = 0; ni < 4; ++ni)
      bfm[ni] = *(const s16x8*)&Bs[(wc + ni * 16 + lr) * 40 + lk];
#pragma unroll
    for (int mi = 0; mi < 4; ++mi)
#pragma unroll
      for (int ni = 0; ni < 4; ++ni)
        acc[mi][ni] = __builtin_amdgcn_mfma_f32_16x16x32_bf16(af[mi], bfm[ni], acc[mi][ni], 0, 0, 0);
  }

#pragma unroll
  for (int mi = 0; mi < 4; ++mi) {
    int rowb = bm + wr + mi * 16 + (lane >> 4) * 4;
#pragma unroll
    for (int ni = 0; ni < 4; ++ni) {
      int col = bn + wc + ni * 16 + lr;
      if (col >= Nc) continue;
#pragma unroll
      for (int r = 0; r < 4; ++r) {
        int row = rowb + r;
        if (row < M) Cb[(size_t)row * Nc + col] = f2bf(acc[mi][ni][r]);
      }
    }
  }
}

// ------------ attention coefficients, hidden layers (C=64,H=4) ------------
__global__ __launch_bounds__(256) void k_att_hid(const u16* __restrict__ hb,
                                                 const float* __restrict__ asw,
                                                 const float* __restrict__ adw,
                                                 float* __restrict__ asrc,
                                                 float* __restrict__ adst) {
  int wid = blockIdx.x * 4 + (threadIdx.x >> 6);
  int lane = threadIdx.x & 63;
  if (wid >= NNODES) return;
  const u16* hp = hb + (size_t)wid * 256;
  float v0 = bf2f(hp[lane]), v1 = bf2f(hp[64 + lane]);
  float v2 = bf2f(hp[128 + lane]), v3 = bf2f(hp[192 + lane]);
  float ps0 = v0 * asw[lane],       pd0 = v0 * adw[lane];
  float ps1 = v1 * asw[64 + lane],  pd1 = v1 * adw[64 + lane];
  float ps2 = v2 * asw[128 + lane], pd2 = v2 * adw[128 + lane];
  float ps3 = v3 * asw[192 + lane], pd3 = v3 * adw[192 + lane];
  ps0 = wred_sum(ps0); ps1 = wred_sum(ps1); ps2 = wred_sum(ps2); ps3 = wred_sum(ps3);
  pd0 = wred_sum(pd0); pd1 = wred_sum(pd1); pd2 = wred_sum(pd2); pd3 = wred_sum(pd3);
  if (lane == 0) {
    asrc[wid * 4 + 0] = ps0; asrc[wid * 4 + 1] = ps1;
    asrc[wid * 4 + 2] = ps2; asrc[wid * 4 + 3] = ps3;
    adst[wid * 4 + 0] = pd0; adst[wid * 4 + 1] = pd1;
    adst[wid * 4 + 2] = pd2; adst[wid * 4 + 3] = pd3;
  }
}

// ------------ attention coefficients, layer 2 (C=40,H=4) ------------
__global__ __launch_bounds__(256) void k_att_l2(const u16* __restrict__ hb2,
                                                const float* __restrict__ asw,
                                                const float* __restrict__ adw,
                                                float* __restrict__ asrc,
                                                float* __restrict__ adst) {
  int wid = blockIdx.x * 4 + (threadIdx.x >> 6);
  int lane = threadIdx.x & 63;
  if (wid >= NNODES) return;
  const u16* hp = hb2 + (size_t)wid * 160;
  float ps0 = 0, ps1 = 0, ps2 = 0, ps3 = 0, pd0 = 0, pd1 = 0, pd2 = 0, pd3 = 0;
  if (lane < 40) {
    float v0 = bf2f(hp[lane]), v1 = bf2f(hp[40 + lane]);
    float v2 = bf2f(hp[80 + lane]), v3 = bf2f(hp[120 + lane]);
    ps0 = v0 * asw[lane];       pd0 = v0 * adw[lane];
    ps1 = v1 * asw[40 + lane];  pd1 = v1 * adw[40 + lane];
    ps2 = v2 * asw[80 + lane];  pd2 = v2 * adw[80 + lane];
    ps3 = v3 * asw[120 + lane]; pd3 = v3 * adw[120 + lane];
  }
  ps0 = wred_sum(ps0); ps1 = wred_sum(ps1); ps2 = wred_sum(ps2); ps3 = wred_sum(ps3);
  pd0 = wred_sum(pd0); pd1 = wred_sum(pd1); pd2 = wred_sum(pd2); pd3 = wred_sum(pd3);
  if (lane == 0) {
    asrc[wid * 4 + 0] = ps0; asrc[wid * 4 + 1] = ps1;
    asrc[wid * 4 + 2] = ps2; asrc[wid * 4 + 3] = ps3;
    adst[wid * 4 + 0] = pd0; adst[wid * 4 + 1] = pd1;
    adst[wid * 4 + 2] = pd2; adst[wid * 4 + 3] = pd3;
  }
}

// ---------- GAT aggregate, hidden layers: one wave per node ----------
// pass 1: per-edge-head exp stored to ew (bf16x4); pass 2 reloads (no re-exp).
__global__ __launch_bounds__(256) void k_aggr_hid(const u16* __restrict__ hb,
                                                  const float* __restrict__ asrc,
                                                  const float* __restrict__ adst,
                                                  const int* __restrict__ rowptr,
                                                  const int* __restrict__ colx,
                                                  const float* __restrict__ bias,
                                                  u16* __restrict__ ew,
                                                  float* __restrict__ out) {
  int wid = blockIdx.x * 4 + (threadIdx.x >> 6);
  int lane = threadIdx.x & 63;
  if (wid >= NNODES) return;
  int beg = rowptr[wid], end = rowptr[wid + 1];
  float ad0 = adst[wid * 4 + 0], ad1 = adst[wid * 4 + 1];
  float ad2 = adst[wid * 4 + 2], ad3 = adst[wid * 4 + 3];

  float s0 = 0.f, s1 = 0.f, s2 = 0.f, s3 = 0.f;
  for (int i = beg + lane; i < end; i += 64) {
    int s = colx[i];
    const float* ap = asrc + (size_t)s * 4;
    float e0 = expf(lrelu(ap[0] + ad0, 0.2f));
    float e1 = expf(lrelu(ap[1] + ad1, 0.2f));
    float e2 = expf(lrelu(ap[2] + ad2, 0.2f));
    float e3 = expf(lrelu(ap[3] + ad3, 0.2f));
    ushort4 w4 = {f2bf(e0), f2bf(e1), f2bf(e2), f2bf(e3)};
    *(ushort4*)(ew + (size_t)i * 4) = w4;
    s0 += e0; s1 += e1; s2 += e2; s3 += e3;
  }
  s0 = wred_sum(s0); s1 = wred_sum(s1); s2 = wred_sum(s2); s3 = wred_sum(s3);

  int q = lane >> 4;
  float sq = (q == 0) ? s0 : (q == 1) ? s1 : (q == 2) ? s2 : s3;

  float ax = 0.f, ay = 0.f, az = 0.f, aw = 0.f;
  const u16* hbl = hb + lane * 4;
  int i = beg;
  for (; i + 4 <= end; i += 4) {
    int e0 = colx[i], e1 = colx[i + 1], e2 = colx[i + 2], e3 = colx[i + 3];
    float w0 = bf2f(ew[(size_t)i * 4 + q]);
    float w1 = bf2f(ew[(size_t)(i + 1) * 4 + q]);
    float w2 = bf2f(ew[(size_t)(i + 2) * 4 + q]);
    float w3 = bf2f(ew[(size_t)(i + 3) * 4 + q]);
    ushort4 r0 = *(const ushort4*)(hbl + (size_t)e0 * 256);
    ushort4 r1 = *(const ushort4*)(hbl + (size_t)e1 * 256);
    ushort4 r2 = *(const ushort4*)(hbl + (size_t)e2 * 256);
    ushort4 r3 = *(const ushort4*)(hbl + (size_t)e3 * 256);
    ax = fmaf(w0, bf2f(r0.x), ax); ay = fmaf(w0, bf2f(r0.y), ay);
    az = fmaf(w0, bf2f(r0.z), az); aw = fmaf(w0, bf2f(r0.w), aw);
    ax = fmaf(w1, bf2f(r1.x), ax); ay = fmaf(w1, bf2f(r1.y), ay);
    az = fmaf(w1, bf2f(r1.z), az); aw = fmaf(w1, bf2f(r1.w), aw);
    ax = fmaf(w2, bf2f(r2.x), ax); ay = fmaf(w2, bf2f(r2.y), ay);
    az = fmaf(w2, bf2f(r2.z), az); aw = fmaf(w2, bf2f(r2.w), aw);
    ax = fmaf(w3, bf2f(r3.x), ax); ay = fmaf(w3, bf2f(r3.y), ay);
    az = fmaf(w3, bf2f(r3.z), az); aw = fmaf(w3, bf2f(r3.w), aw);
  }
  for (; i < end; ++i) {
    int e0 = colx[i];
    float w0 = bf2f(ew[(size_t)i * 4 + q]);
    ushort4 r0 = *(const ushort4*)(hbl + (size_t)e0 * 256);
    ax = fmaf(w0, bf2f(r0.x), ax); ay = fmaf(w0, bf2f(r0.y), ay);
    az = fmaf(w0, bf2f(r0.z), az); aw = fmaf(w0, bf2f(r0.w), aw);
  }
  float inv = 1.f / (sq + 1e-16f);
  float4 b4 = ((const float4*)bias)[lane];
  float4 o = {fmaf(ax, inv, b4.x), fmaf(ay, inv, b4.y),
              fmaf(az, inv, b4.z), fmaf(aw, inv, b4.w)};
  ((float4*)out)[(size_t)wid * 64 + lane] = o;
}

// ---- layer-2 aggregate + head-mean + bias + log_softmax (fused) ----
__global__ __launch_bounds__(256) void k_aggr_l2(const u16* __restrict__ hb2,
                                                 const float* __restrict__ asrc,
                                                 const float* __restrict__ adst,
                                                 const int* __restrict__ rowptr,
                                                 const int* __restrict__ colx,
                                                 const float* __restrict__ b2,
                                                 u16* __restrict__ ew,
                                                 float* __restrict__ out) {
  __shared__ float tile[4][160];
  int wv = threadIdx.x >> 6;
  int wid = blockIdx.x * 4 + wv;
  int lane = threadIdx.x & 63;
  bool valid = (wid < NNODES);
  int beg = 0, end = 0;
  float ad0 = 0, ad1 = 0, ad2 = 0, ad3 = 0;
  if (valid) {
    beg = rowptr[wid]; end = rowptr[wid + 1];
    ad0 = adst[wid * 4 + 0]; ad1 = adst[wid * 4 + 1];
    ad2 = adst[wid * 4 + 2]; ad3 = adst[wid * 4 + 3];
  }
  float s0 = 0.f, s1 = 0.f, s2 = 0.f, s3 = 0.f;
  for (int i = beg + lane; i < end; i += 64) {
    int s = colx[i];
    const float* ap = asrc + (size_t)s * 4;
    float e0 = expf(lrelu(ap[0] + ad0, 0.2f));
    float e1 = expf(lrelu(ap[1] + ad1, 0.2f));
    float e2 = expf(lrelu(ap[2] + ad2, 0.2f));
    float e3 = expf(lrelu(ap[3] + ad3, 0.2f));
    ushort4 w4 = {f2bf(e0), f2bf(e1), f2bf(e2), f2bf(e3)};
    *(ushort4*)(ew + (size_t)i * 4) = w4;
    s0 += e0; s1 += e1; s2 += e2; s3 += e3;
  }
  s0 = wred_sum(s0); s1 = wred_sum(s1); s2 = wred_sum(s2); s3 = wred_sum(s3);

  int q = lane / 10; if (q > 3) q = 3;
  float sq = (q == 0) ? s0 : (q == 1) ? s1 : (q == 2) ? s2 : s3;

  float ax = 0.f, ay = 0.f, az = 0.f, aw = 0.f;
  const u16* hbl = hb2 + lane * 4;
  int i = beg;
  for (; i + 4 <= end; i += 4) {
    int e0 = colx[i], e1 = colx[i + 1], e2 = colx[i + 2], e3 = colx[i + 3];
    float w0 = bf2f(ew[(size_t)i * 4 + q]);
    float w1 = bf2f(ew[(size_t)(i + 1) * 4 + q]);
    float w2 = bf2f(ew[(size_t)(i + 2) * 4 + q]);
    float w3 = bf2f(ew[(size_t)(i + 3) * 4 + q]);
    if (lane < 40) {
      ushort4 r0 = *(const ushort4*)(hbl + (size_t)e0 * 160);
      ushort4 r1 = *(const ushort4*)(hbl + (size_t)e1 * 160);
      ushort4 r2 = *(const ushort4*)(hbl + (size_t)e2 * 160);
      ushort4 r3 = *(const ushort4*)(hbl + (size_t)e3 * 160);
      ax = fmaf(w0, bf2f(r0.x), ax); ay = fmaf(w0, bf2f(r0.y), ay);
      az = fmaf(w0, bf2f(r0.z), az); aw = fmaf(w0, bf2f(r0.w), aw);
      ax = fmaf(w1, bf2f(r1.x), ax); ay = fmaf(w1, bf2f(r1.y), ay);
      az = fmaf(w1, bf2f(r1.z), az); aw = fmaf(w1, bf2f(r1.w), aw);
      ax = fmaf(w2, bf2f(r2.x), ax); ay = fmaf(w2, bf2f(r2.y), ay);
      az = fmaf(w2, bf2f(r2.z), az); aw = fmaf(w2, bf2f(r2.w), aw);
      ax = fmaf(w3, bf2f(r3.x), ax); ay = fmaf(w3, bf2f(r3.y), ay);
      az = fmaf(w3, bf2f(r3.z), az); aw = fmaf(w3, bf2f(r3.w), aw);
    }
  }
  for (; i < end; ++i) {
    int e0 = colx[i];
    float w0 = bf2f(ew[(size_t)i * 4 + q]);
    if (lane < 40) {
      ushort4 r0 = *(const ushort4*)(hbl + (size_t)e0 * 160);
      ax = fmaf(w0, bf2f(r0.x), ax); ay = fmaf(w0, bf2f(r0.y), ay);
      az = fmaf(w0, bf2f(r0.z), az); aw = fmaf(w0, bf2f(r0.w), aw);
    }
  }
  if (valid && lane < 40) {
    float inv = 1.f / (sq + 1e-16f);
    tile[wv][lane * 4 + 0] = ax * inv;
    tile[wv][lane * 4 + 1] = ay * inv;
    tile[wv][lane * 4 + 2] = az * inv;
    tile[wv][lane * 4 + 3] = aw * inv;
  }
  __syncthreads();
  int c = lane;
  float val = -3.0e38f;
  if (valid && c < 40) {
    val = 0.25f * (tile[wv][c] + tile[wv][c + 40] + tile[wv][c + 80] + tile[wv][c + 120]) + b2[c];
  }
  float mv = (valid && c < 40) ? val : -3.0e38f;
  mv = wred_max(mv);
  float ex = (valid && c < 40) ? expf(val - mv) : 0.f;
  ex = wred_sum(ex);
  if (valid && c < 40) out[(size_t)wid * 40 + c] = val - mv - logf(ex);
}

// ---------------- batch norm (stats + coefficients only; apply fused in GEMM) ----------------
__global__ __launch_bounds__(256) void k_bnstats(const float* __restrict__ x,
                                                 float* __restrict__ stat) {
  int c = threadIdx.x;
  const int rows = (NNODES + gridDim.x - 1) / gridDim.x;
  int r0 = blockIdx.x * rows;
  int r1 = min(NNODES, r0 + rows);
  float s = 0.f, qq = 0.f;
  for (int r = r0; r < r1; ++r) {
    float v = x[(size_t)r * 256 + c];
    s += v;
    qq = fmaf(v, v, qq);
  }
  atomicAdd(&stat[c], s);
  atomicAdd(&stat[256 + c], qq);
}

__global__ void k_bnfin(const float* __restrict__ stat, const float* __restrict__ g,
                        const float* __restrict__ be, float* __restrict__ sc,
                        float* __restrict__ sh) {
  int c = threadIdx.x;
  float mean = stat[c] * (1.0f / NNODES);
  float var = stat[256 + c] * (1.0f / NNODES) - mean * mean;
  float inv = rsqrtf(var + 1e-5f);
  float a = g[c] * inv;
  sc[c] = a;
  sh[c] = be[c] - mean * a;
}

// ---------------- launch ----------------
extern "C" void kernel_launch(void* const* d_in, const int* in_sizes, int n_in,
                              void* d_out, int out_size, void* d_ws, size_t ws_size,
                              hipStream_t stream) {
  const float* x   = (const float*)d_in[0];
  const int*   adj = (const int*)d_in[1];
  const float* W0  = (const float*)d_in[2];
  const float* as0 = (const float*)d_in[3];
  const float* ad0 = (const float*)d_in[4];
  const float* b0  = (const float*)d_in[5];
  const float* W1  = (const float*)d_in[6];
  const float* as1 = (const float*)d_in[7];
  const float* ad1 = (const float*)d_in[8];
  const float* b1  = (const float*)d_in[9];
  const float* W2  = (const float*)d_in[10];
  const float* as2 = (const float*)d_in[11];
  const float* ad2 = (const float*)d_in[12];
  const float* b2  = (const float*)d_in[13];
  const float* g0  = (const float*)d_in[14];
  const float* be0 = (const float*)d_in[15];
  const float* g1  = (const float*)d_in[16];
  const float* be1 = (const float*)d_in[17];
  float* out = (float*)d_out;

  float* ws   = (float*)d_ws;
  float* bufA = ws;                                  // N*256 f32 (raw aggr output)
  float* asrc = bufA + (size_t)NNODES * 256;         // N*4
  float* adst = asrc + (size_t)NNODES * 4;           // N*4
  float* stat = adst + (size_t)NNODES * 4;           // 512
  float* bnsc = stat + 512;                          // 256
  float* bnsh = bnsc + 256;                          // 256
  u16*   hb   = (u16*)(bnsh + 256);                  // N*256 bf16 (h payload)
  u16*   w0t  = hb + (size_t)NNODES * 256;           // 256*128 bf16 (W0^T)
  u16*   w1t  = w0t + 256 * 128;                     // 256*256 bf16 (W1^T)
  u16*   w2t  = w1t + 256 * 256;                     // 160*256 bf16 (W2^T)
  u16*   ew   = w2t + 160 * 256;                     // EPTOT*4 bf16 (edge weights)
  int* rowptr = (int*)(ew + (size_t)EPTOT * 4);      // N+1
  int* fill   = rowptr + (NNODES + 1);               // N
  int* colx   = fill + NNODES;                       // EPTOT
  int* deg    = colx + EPTOT;                        // N
  int* part   = deg + NNODES;                        // N
  int* bsum   = part + NNODES;                       // SCAN_NB

  // CSR build (by destination), self-loops appended as edges E..E+N-1
  hipMemsetAsync(deg, 0, NNODES * sizeof(int), stream);
  k_hist<<<(EPTOT + 255) / 256, 256, 0, stream>>>(adj, deg);
  k_scan1<<<SCAN_NB, 256, 0, stream>>>(deg, part, bsum);
  k_scan2<<<1, 256, 0, stream>>>(bsum);
  k_scan3<<<SCAN_NB, 256, 0, stream>>>(part, bsum, rowptr, fill);
  k_fill<<<(EPTOT + 255) / 256, 256, 0, stream>>>(adj, fill, colx);

  // weight transpose+convert (tiny)
  k_wt<<<(128 * 256 + 255) / 256, 256, 0, stream>>>(W0, w0t, 128, 256);
  k_wt<<<(256 * 256 + 255) / 256, 256, 0, stream>>>(W1, w1t, 256, 256);
  k_wt<<<(256 * 160 + 255) / 256, 256, 0, stream>>>(W2, w2t, 256, 160);

  dim3 gg2((NNODES + 127) / 128, 2);

  // layer 0 (K=128)
  k_gemm_mfma<<<gg2, 256, 0, stream>>>(x, w0t, hb, nullptr, nullptr, NNODES, 128, 256);
  k_att_hid<<<12500, 256, 0, stream>>>(hb, as0, ad0, asrc, adst);
  k_aggr_hid<<<12500, 256, 0, stream>>>(hb, asrc, adst, rowptr, colx, b0, ew, bufA);
  hipMemsetAsync(stat, 0, 512 * sizeof(float), stream);
  k_bnstats<<<400, 256, 0, stream>>>(bufA, stat);
  k_bnfin<<<1, 256, 0, stream>>>(stat, g0, be0, bnsc, bnsh);

  // layer 1 (K=256): BN0+LeakyReLU fused into GEMM A-staging
  k_gemm_mfma<<<gg2, 256, 0, stream>>>(bufA, w1t, hb, bnsc, bnsh, NNODES, 256, 256);
  k_att_hid<<<12500, 256, 0, stream>>>(hb, as1, ad1, asrc, adst);
  k_aggr_hid<<<12500, 256, 0, stream>>>(hb, asrc, adst, rowptr, colx, b1, ew, bufA);
  hipMemsetAsync(stat, 0, 512 * sizeof(float), stream);
  k_bnstats<<<400, 256, 0, stream>>>(bufA, stat);
  k_bnfin<<<1, 256, 0, stream>>>(stat, g1, be1, bnsc, bnsh);

  // layer 2 (K=256, Nc=160): BN1+LeakyReLU fused; + fused log_softmax epilogue
  k_gemm_mfma<<<gg2, 256, 0, stream>>>(bufA, w2t, hb, bnsc, bnsh, NNODES, 256, 160);
  k_att_l2<<<12500, 256, 0, stream>>>(hb, as2, ad2, asrc, adst);
  k_aggr_l2<<<12500, 256, 0, stream>>>(hb, asrc, adst, rowptr, colx, b2, ew, out);
}

// Round 6
// 565.808 us; speedup vs baseline: 1.8492x; 1.0165x over previous
//
#include <hip/hip_runtime.h>

#define NNODES 50000
#define NEDGES 800000
#define EPTOT  (NEDGES + NNODES)
#define SCAN_NB ((NNODES + 255) / 256)

typedef unsigned short u16;
typedef unsigned int   u32;
typedef __attribute__((ext_vector_type(8))) short s16x8;
typedef __attribute__((ext_vector_type(4))) float f32x4;

static __device__ __forceinline__ float lrelu(float x, float s) { return x > 0.f ? x : s * x; }
static __device__ __forceinline__ float bf2f(u16 b) { return __uint_as_float((u32)b << 16); }
static __device__ __forceinline__ u16 f2bf(float f) {
  u32 u = __float_as_uint(f);
  u32 r = (u + 0x7FFFu + ((u >> 16) & 1u)) >> 16;  // round-nearest-even
  return (u16)r;
}

__device__ __forceinline__ float wred_max(float v) {
#pragma unroll
  for (int off = 32; off; off >>= 1) v = fmaxf(v, __shfl_xor(v, off));
  return v;
}
__device__ __forceinline__ float wred_sum(float v) {
#pragma unroll
  for (int off = 32; off; off >>= 1) v += __shfl_xor(v, off);
  return v;
}

// ---------------- CSR build ----------------
__global__ void k_hist(const int* __restrict__ adj, int* __restrict__ deg) {
  int i = blockIdx.x * blockDim.x + threadIdx.x;
  if (i >= EPTOT) return;
  int d = (i < NEDGES) ? adj[NEDGES + i] : (i - NEDGES);
  atomicAdd(&deg[d], 1);
}

__global__ __launch_bounds__(256) void k_scan1(const int* __restrict__ deg,
                                               int* __restrict__ part,
                                               int* __restrict__ bsum) {
  __shared__ int sm[256];
  int t = threadIdx.x;
  int i = blockIdx.x * 256 + t;
  int v = (i < NNODES) ? deg[i] : 0;
  sm[t] = v;
  __syncthreads();
#pragma unroll
  for (int off = 1; off < 256; off <<= 1) {
    int u = (t >= off) ? sm[t - off] : 0;
    __syncthreads();
    sm[t] += u;
    __syncthreads();
  }
  if (i < NNODES) part[i] = sm[t] - v;
  if (t == 255) bsum[blockIdx.x] = sm[255];
}

__global__ __launch_bounds__(256) void k_scan2(int* __restrict__ bsum) {
  __shared__ int sm[256];
  int t = threadIdx.x;
  int v = (t < SCAN_NB) ? bsum[t] : 0;
  sm[t] = v;
  __syncthreads();
#pragma unroll
  for (int off = 1; off < 256; off <<= 1) {
    int u = (t >= off) ? sm[t - off] : 0;
    __syncthreads();
    sm[t] += u;
    __syncthreads();
  }
  if (t < SCAN_NB) bsum[t] = sm[t] - v;
}

__global__ __launch_bounds__(256) void k_scan3(const int* __restrict__ part,
                                               const int* __restrict__ bsum,
                                               int* __restrict__ rowptr,
                                               int* __restrict__ fill) {
  int i = blockIdx.x * 256 + threadIdx.x;
  if (i == 0) rowptr[NNODES] = EPTOT;
  if (i >= NNODES) return;
  int r = part[i] + bsum[blockIdx.x];
  rowptr[i] = r;
  fill[i] = r;
}

__global__ void k_fill(const int* __restrict__ adj, int* __restrict__ fill,
                       int* __restrict__ colx) {
  int i = blockIdx.x * blockDim.x + threadIdx.x;
  if (i >= EPTOT) return;
  int s, d;
  if (i < NEDGES) { s = adj[i]; d = adj[NEDGES + i]; }
  else            { s = i - NEDGES; d = s; }
  int pos = atomicAdd(&fill[d], 1);
  colx[pos] = s;
}

// ---- transpose+convert W[K,Nc](f32) -> Wt[Nc,K](bf16) ----
__global__ void k_wt(const float* __restrict__ W, u16* __restrict__ Wt, int K, int Nc) {
  int i = blockIdx.x * blockDim.x + threadIdx.x;
  if (i >= K * Nc) return;
  int n = i % Nc, k = i / Nc;
  Wt[(size_t)n * K + k] = f2bf(W[i]);
}

// ---- A-chunk loader: 8 elements along K, optional BN+LeakyReLU transform ----
template <int ABF>
__device__ __forceinline__ void load_a_chunk(const void* __restrict__ Av, int ga, int M,
                                             int K, int koff, const float* __restrict__ sc,
                                             const float* __restrict__ sh,
                                             ushort4& lo, ushort4& hi) {
  float f[8];
  if (ABF) {
    uint4 av = {0, 0, 0, 0};
    if (ga < M) av = *(const uint4*)((const u16*)Av + (size_t)ga * K + koff);
    u32 w[4] = {av.x, av.y, av.z, av.w};
#pragma unroll
    for (int j = 0; j < 4; ++j) {
      f[2 * j]     = bf2f((u16)(w[j] & 0xffffu));
      f[2 * j + 1] = bf2f((u16)(w[j] >> 16));
    }
  } else {
    float4 a0 = {0, 0, 0, 0}, a1 = {0, 0, 0, 0};
    if (ga < M) {
      const float* p = (const float*)Av + (size_t)ga * K + koff;
      a0 = *(const float4*)p;
      a1 = *(const float4*)(p + 4);
    }
    f[0] = a0.x; f[1] = a0.y; f[2] = a0.z; f[3] = a0.w;
    f[4] = a1.x; f[5] = a1.y; f[6] = a1.z; f[7] = a1.w;
  }
  if (sc) {
#pragma unroll
    for (int j = 0; j < 8; ++j) f[j] = lrelu(fmaf(f[j], sc[koff + j], sh[koff + j]), 0.1f);
  }
  lo = (ushort4){f2bf(f[0]), f2bf(f[1]), f2bf(f[2]), f2bf(f[3])};
  hi = (ushort4){f2bf(f[4]), f2bf(f[5]), f2bf(f[6]), f2bf(f[7])};
}

// -------- MFMA GEMM: Cb[M,Nc](bf16) = act(A[M,K]) @ Wt[Nc,K](bf16)^T --------
// ABF: A is bf16 (else f32). sc!=null: fused BN+LeakyReLU(0.1) on A.
// ATT: fused attention coefficients (64-col heads): asrc/adst += acc . asw/adw
// (exactly one atomicAdd per (row,head) -> deterministic).
template <int ABF, int ATT>
__global__ __launch_bounds__(256) void k_gemm_mfma(const void* __restrict__ Av,
                                                   const u16* __restrict__ Wt,
                                                   u16* __restrict__ Cb,
                                                   const float* __restrict__ sc,
                                                   const float* __restrict__ sh,
                                                   const float* __restrict__ asw,
                                                   const float* __restrict__ adw,
                                                   float* __restrict__ asrc,
                                                   float* __restrict__ adst,
                                                   int M, int K, int Nc) {
  __shared__ u16 As[128 * 40];  // rows padded to 40 bf16 (80B) -> <=2-way bank alias
  __shared__ u16 Bs[128 * 40];
  const int tid = threadIdx.x;
  const int lane = tid & 63;
  const int wv = tid >> 6;
  const int wr = (wv >> 1) * 64, wc = (wv & 1) * 64;
  const int lr = lane & 15, lk = (lane >> 4) * 8;
  const int bm = blockIdx.x * 128, bn = blockIdx.y * 128;

  const int row0 = tid >> 2, kc0 = (tid & 3) * 8;
  const int ch1 = tid + 256;
  const int row1 = ch1 >> 2, kc1 = (ch1 & 3) * 8;

  f32x4 acc[4][4];
#pragma unroll
  for (int i = 0; i < 4; ++i)
#pragma unroll
    for (int j = 0; j < 4; ++j) {
      f32x4 z = {0.f, 0.f, 0.f, 0.f};
      acc[i][j] = z;
    }

  for (int k0 = 0; k0 < K; k0 += 32) {
    ushort4 h00, h01, h10, h11;
    uint4 bv0 = {0, 0, 0, 0}, bv1 = {0, 0, 0, 0};
    load_a_chunk<ABF>(Av, bm + row0, M, K, k0 + kc0, sc, sh, h00, h01);
    load_a_chunk<ABF>(Av, bm + row1, M, K, k0 + kc1, sc, sh, h10, h11);
    if (bn + row0 < Nc) bv0 = *(const uint4*)(Wt + (size_t)(bn + row0) * K + k0 + kc0);
    if (bn + row1 < Nc) bv1 = *(const uint4*)(Wt + (size_t)(bn + row1) * K + k0 + kc1);

    __syncthreads();
    *(ushort4*)&As[row0 * 40 + kc0]     = h00;
    *(ushort4*)&As[row0 * 40 + kc0 + 4] = h01;
    *(ushort4*)&As[row1 * 40 + kc1]     = h10;
    *(ushort4*)&As[row1 * 40 + kc1 + 4] = h11;
    *(uint4*)&Bs[row0 * 40 + kc0] = bv0;
    *(uint4*)&Bs[row1 * 40 + kc1] = bv1;
    __syncthreads();

    s16x8 af[4], bfm[4];
#pragma unroll
    for (int mi = 0; mi < 4; ++mi)
      af[mi] = *(const s16x8*)&As[(wr + mi * 16 + lr) * 40 + lk];
#pragma unroll
    for (int ni = 0; ni < 4; ++ni)
      bfm[ni] = *(const s16x8*)&Bs[(wc + ni * 16 + lr) * 40 + lk];
#pragma unroll
    for (int mi = 0; mi < 4; ++mi)
#pragma unroll
      for (int ni = 0; ni < 4; ++ni)
        acc[mi][ni] = __builtin_amdgcn_mfma_f32_16x16x32_bf16(af[mi], bfm[ni], acc[mi][ni], 0, 0, 0);
  }

  // C-write: D col = lane&15, row = (lane>>4)*4 + reg
#pragma unroll
  for (int mi = 0; mi < 4; ++mi) {
    int rowb = bm + wr + mi * 16 + (lane >> 4) * 4;
#pragma unroll
    for (int ni = 0; ni < 4; ++ni) {
      int col = bn + wc + ni * 16 + lr;
      if (col >= Nc) continue;
#pragma unroll
      for (int r = 0; r < 4; ++r) {
        int row = rowb + r;
        if (row < M) Cb[(size_t)row * Nc + col] = f2bf(acc[mi][ni][r]);
      }
    }
  }

  if (ATT) {
    int head = (bn + wc) >> 6;  // all this wave's cols lie in one 64-col head
#pragma unroll
    for (int mi = 0; mi < 4; ++mi) {
#pragma unroll
      for (int r = 0; r < 4; ++r) {
        int row = bm + wr + mi * 16 + (lane >> 4) * 4 + r;
        float s = 0.f, d = 0.f;
#pragma unroll
        for (int ni = 0; ni < 4; ++ni) {
          int col = bn + wc + ni * 16 + lr;
          float v = acc[mi][ni][r];
          s = fmaf(v, asw[col], s);
          d = fmaf(v, adw[col], d);
        }
#pragma unroll
        for (int off = 1; off < 16; off <<= 1) {
          s += __shfl_xor(s, off);
          d += __shfl_xor(d, off);
        }
        if (lr == 0 && row < M) {
          atomicAdd(&asrc[(size_t)row * 4 + head], s);
          atomicAdd(&adst[(size_t)row * 4 + head], d);
        }
      }
    }
  }
}

// ------------ attention coefficients, layer 2 (C=40,H=4) ------------
__global__ __launch_bounds__(256) void k_att_l2(const u16* __restrict__ hb2,
                                                const float* __restrict__ asw,
                                                const float* __restrict__ adw,
                                                float* __restrict__ asrc,
                                                float* __restrict__ adst) {
  int wid = blockIdx.x * 4 + (threadIdx.x >> 6);
  int lane = threadIdx.x & 63;
  if (wid >= NNODES) return;
  const u16* hp = hb2 + (size_t)wid * 160;
  float ps0 = 0, ps1 = 0, ps2 = 0, ps3 = 0, pd0 = 0, pd1 = 0, pd2 = 0, pd3 = 0;
  if (lane < 40) {
    float v0 = bf2f(hp[lane]), v1 = bf2f(hp[40 + lane]);
    float v2 = bf2f(hp[80 + lane]), v3 = bf2f(hp[120 + lane]);
    ps0 = v0 * asw[lane];       pd0 = v0 * adw[lane];
    ps1 = v1 * asw[40 + lane];  pd1 = v1 * adw[40 + lane];
    ps2 = v2 * asw[80 + lane];  pd2 = v2 * adw[80 + lane];
    ps3 = v3 * asw[120 + lane]; pd3 = v3 * adw[120 + lane];
  }
  ps0 = wred_sum(ps0); ps1 = wred_sum(ps1); ps2 = wred_sum(ps2); ps3 = wred_sum(ps3);
  pd0 = wred_sum(pd0); pd1 = wred_sum(pd1); pd2 = wred_sum(pd2); pd3 = wred_sum(pd3);
  if (lane == 0) {
    asrc[wid * 4 + 0] = ps0; asrc[wid * 4 + 1] = ps1;
    asrc[wid * 4 + 2] = ps2; asrc[wid * 4 + 3] = ps3;
    adst[wid * 4 + 0] = pd0; adst[wid * 4 + 1] = pd1;
    adst[wid * 4 + 2] = pd2; adst[wid * 4 + 3] = pd3;
  }
}

// ---------- GAT aggregate, hidden layers: one wave per node ----------
// pass 1: per-edge-head exp stored to ew (bf16x4); pass 2 reloads (no re-exp).
// Output: bf16 (bias included).
__global__ __launch_bounds__(256) void k_aggr_hid(const u16* __restrict__ hb,
                                                  const float* __restrict__ asrc,
                                                  const float* __restrict__ adst,
                                                  const int* __restrict__ rowptr,
                                                  const int* __restrict__ colx,
                                                  const float* __restrict__ bias,
                                                  u16* __restrict__ ew,
                                                  u16* __restrict__ outb) {
  int wid = blockIdx.x * 4 + (threadIdx.x >> 6);
  int lane = threadIdx.x & 63;
  if (wid >= NNODES) return;
  int beg = rowptr[wid], end = rowptr[wid + 1];
  float ad0 = adst[wid * 4 + 0], ad1 = adst[wid * 4 + 1];
  float ad2 = adst[wid * 4 + 2], ad3 = adst[wid * 4 + 3];

  float s0 = 0.f, s1 = 0.f, s2 = 0.f, s3 = 0.f;
  for (int i = beg + lane; i < end; i += 64) {
    int s = colx[i];
    const float* ap = asrc + (size_t)s * 4;
    float e0 = expf(lrelu(ap[0] + ad0, 0.2f));
    float e1 = expf(lrelu(ap[1] + ad1, 0.2f));
    float e2 = expf(lrelu(ap[2] + ad2, 0.2f));
    float e3 = expf(lrelu(ap[3] + ad3, 0.2f));
    ushort4 w4 = {f2bf(e0), f2bf(e1), f2bf(e2), f2bf(e3)};
    *(ushort4*)(ew + (size_t)i * 4) = w4;
    s0 += e0; s1 += e1; s2 += e2; s3 += e3;
  }
  s0 = wred_sum(s0); s1 = wred_sum(s1); s2 = wred_sum(s2); s3 = wred_sum(s3);

  int q = lane >> 4;
  float sq = (q == 0) ? s0 : (q == 1) ? s1 : (q == 2) ? s2 : s3;

  float ax = 0.f, ay = 0.f, az = 0.f, aw = 0.f;
  const u16* hbl = hb + lane * 4;
  int i = beg;
  for (; i + 4 <= end; i += 4) {
    int e0 = colx[i], e1 = colx[i + 1], e2 = colx[i + 2], e3 = colx[i + 3];
    float w0 = bf2f(ew[(size_t)i * 4 + q]);
    float w1 = bf2f(ew[(size_t)(i + 1) * 4 + q]);
    float w2 = bf2f(ew[(size_t)(i + 2) * 4 + q]);
    float w3 = bf2f(ew[(size_t)(i + 3) * 4 + q]);
    ushort4 r0 = *(const ushort4*)(hbl + (size_t)e0 * 256);
    ushort4 r1 = *(const ushort4*)(hbl + (size_t)e1 * 256);
    ushort4 r2 = *(const ushort4*)(hbl + (size_t)e2 * 256);
    ushort4 r3 = *(const ushort4*)(hbl + (size_t)e3 * 256);
    ax = fmaf(w0, bf2f(r0.x), ax); ay = fmaf(w0, bf2f(r0.y), ay);
    az = fmaf(w0, bf2f(r0.z), az); aw = fmaf(w0, bf2f(r0.w), aw);
    ax = fmaf(w1, bf2f(r1.x), ax); ay = fmaf(w1, bf2f(r1.y), ay);
    az = fmaf(w1, bf2f(r1.z), az); aw = fmaf(w1, bf2f(r1.w), aw);
    ax = fmaf(w2, bf2f(r2.x), ax); ay = fmaf(w2, bf2f(r2.y), ay);
    az = fmaf(w2, bf2f(r2.z), az); aw = fmaf(w2, bf2f(r2.w), aw);
    ax = fmaf(w3, bf2f(r3.x), ax); ay = fmaf(w3, bf2f(r3.y), ay);
    az = fmaf(w3, bf2f(r3.z), az); aw = fmaf(w3, bf2f(r3.w), aw);
  }
  for (; i < end; ++i) {
    int e0 = colx[i];
    float w0 = bf2f(ew[(size_t)i * 4 + q]);
    ushort4 r0 = *(const ushort4*)(hbl + (size_t)e0 * 256);
    ax = fmaf(w0, bf2f(r0.x), ax); ay = fmaf(w0, bf2f(r0.y), ay);
    az = fmaf(w0, bf2f(r0.z), az); aw = fmaf(w0, bf2f(r0.w), aw);
  }
  float inv = 1.f / (sq + 1e-16f);
  float4 b4 = ((const float4*)bias)[lane];
  ushort4 o = {f2bf(fmaf(ax, inv, b4.x)), f2bf(fmaf(ay, inv, b4.y)),
               f2bf(fmaf(az, inv, b4.z)), f2bf(fmaf(aw, inv, b4.w))};
  ((ushort4*)outb)[(size_t)wid * 64 + lane] = o;
}

// ---- layer-2 aggregate + head-mean + bias + log_softmax (fused) ----
__global__ __launch_bounds__(256) void k_aggr_l2(const u16* __restrict__ hb2,
                                                 const float* __restrict__ asrc,
                                                 const float* __restrict__ adst,
                                                 const int* __restrict__ rowptr,
                                                 const int* __restrict__ colx,
                                                 const float* __restrict__ b2,
                                                 u16* __restrict__ ew,
                                                 float* __restrict__ out) {
  __shared__ float tile[4][160];
  int wv = threadIdx.x >> 6;
  int wid = blockIdx.x * 4 + wv;
  int lane = threadIdx.x & 63;
  bool valid = (wid < NNODES);
  int beg = 0, end = 0;
  float ad0 = 0, ad1 = 0, ad2 = 0, ad3 = 0;
  if (valid) {
    beg = rowptr[wid]; end = rowptr[wid + 1];
    ad0 = adst[wid * 4 + 0]; ad1 = adst[wid * 4 + 1];
    ad2 = adst[wid * 4 + 2]; ad3 = adst[wid * 4 + 3];
  }
  float s0 = 0.f, s1 = 0.f, s2 = 0.f, s3 = 0.f;
  for (int i = beg + lane; i < end; i += 64) {
    int s = colx[i];
    const float* ap = asrc + (size_t)s * 4;
    float e0 = expf(lrelu(ap[0] + ad0, 0.2f));
    float e1 = expf(lrelu(ap[1] + ad1, 0.2f));
    float e2 = expf(lrelu(ap[2] + ad2, 0.2f));
    float e3 = expf(lrelu(ap[3] + ad3, 0.2f));
    ushort4 w4 = {f2bf(e0), f2bf(e1), f2bf(e2), f2bf(e3)};
    *(ushort4*)(ew + (size_t)i * 4) = w4;
    s0 += e0; s1 += e1; s2 += e2; s3 += e3;
  }
  s0 = wred_sum(s0); s1 = wred_sum(s1); s2 = wred_sum(s2); s3 = wred_sum(s3);

  int q = lane / 10; if (q > 3) q = 3;
  float sq = (q == 0) ? s0 : (q == 1) ? s1 : (q == 2) ? s2 : s3;

  float ax = 0.f, ay = 0.f, az = 0.f, aw = 0.f;
  const u16* hbl = hb2 + lane * 4;
  int i = beg;
  for (; i + 4 <= end; i += 4) {
    int e0 = colx[i], e1 = colx[i + 1], e2 = colx[i + 2], e3 = colx[i + 3];
    float w0 = bf2f(ew[(size_t)i * 4 + q]);
    float w1 = bf2f(ew[(size_t)(i + 1) * 4 + q]);
    float w2 = bf2f(ew[(size_t)(i + 2) * 4 + q]);
    float w3 = bf2f(ew[(size_t)(i + 3) * 4 + q]);
    if (lane < 40) {
      ushort4 r0 = *(const ushort4*)(hbl + (size_t)e0 * 160);
      ushort4 r1 = *(const ushort4*)(hbl + (size_t)e1 * 160);
      ushort4 r2 = *(const ushort4*)(hbl + (size_t)e2 * 160);
      ushort4 r3 = *(const ushort4*)(hbl + (size_t)e3 * 160);
      ax = fmaf(w0, bf2f(r0.x), ax); ay = fmaf(w0, bf2f(r0.y), ay);
      az = fmaf(w0, bf2f(r0.z), az); aw = fmaf(w0, bf2f(r0.w), aw);
      ax = fmaf(w1, bf2f(r1.x), ax); ay = fmaf(w1, bf2f(r1.y), ay);
      az = fmaf(w1, bf2f(r1.z), az); aw = fmaf(w1, bf2f(r1.w), aw);
      ax = fmaf(w2, bf2f(r2.x), ax); ay = fmaf(w2, bf2f(r2.y), ay);
      az = fmaf(w2, bf2f(r2.z), az); aw = fmaf(w2, bf2f(r2.w), aw);
      ax = fmaf(w3, bf2f(r3.x), ax); ay = fmaf(w3, bf2f(r3.y), ay);
      az = fmaf(w3, bf2f(r3.z), az); aw = fmaf(w3, bf2f(r3.w), aw);
    }
  }
  for (; i < end; ++i) {
    int e0 = colx[i];
    float w0 = bf2f(ew[(size_t)i * 4 + q]);
    if (lane < 40) {
      ushort4 r0 = *(const ushort4*)(hbl + (size_t)e0 * 160);
      ax = fmaf(w0, bf2f(r0.x), ax); ay = fmaf(w0, bf2f(r0.y), ay);
      az = fmaf(w0, bf2f(r0.z), az); aw = fmaf(w0, bf2f(r0.w), aw);
    }
  }
  if (valid && lane < 40) {
    float inv = 1.f / (sq + 1e-16f);
    tile[wv][lane * 4 + 0] = ax * inv;
    tile[wv][lane * 4 + 1] = ay * inv;
    tile[wv][lane * 4 + 2] = az * inv;
    tile[wv][lane * 4 + 3] = aw * inv;
  }
  __syncthreads();
  int c = lane;
  float val = -3.0e38f;
  if (valid && c < 40) {
    val = 0.25f * (tile[wv][c] + tile[wv][c + 40] + tile[wv][c + 80] + tile[wv][c + 120]) + b2[c];
  }
  float mv = (valid && c < 40) ? val : -3.0e38f;
  mv = wred_max(mv);
  float ex = (valid && c < 40) ? expf(val - mv) : 0.f;
  ex = wred_sum(ex);
  if (valid && c < 40) out[(size_t)wid * 40 + c] = val - mv - logf(ex);
}

// ---------------- batch norm (stats from bf16; apply fused in GEMM) ----------------
__global__ __launch_bounds__(256) void k_bnstats(const u16* __restrict__ x,
                                                 float* __restrict__ stat) {
  int c = threadIdx.x;
  const int rows = (NNODES + gridDim.x - 1) / gridDim.x;
  int r0 = blockIdx.x * rows;
  int r1 = min(NNODES, r0 + rows);
  float s = 0.f, qq = 0.f;
  for (int r = r0; r < r1; ++r) {
    float v = bf2f(x[(size_t)r * 256 + c]);
    s += v;
    qq = fmaf(v, v, qq);
  }
  atomicAdd(&stat[c], s);
  atomicAdd(&stat[256 + c], qq);
}

__global__ void k_bnfin(const float* __restrict__ stat, const float* __restrict__ g,
                        const float* __restrict__ be, float* __restrict__ sc,
                        float* __restrict__ sh) {
  int c = threadIdx.x;
  float mean = stat[c] * (1.0f / NNODES);
  float var = stat[256 + c] * (1.0f / NNODES) - mean * mean;
  float inv = rsqrtf(var + 1e-5f);
  float a = g[c] * inv;
  sc[c] = a;
  sh[c] = be[c] - mean * a;
}

// ---------------- launch ----------------
extern "C" void kernel_launch(void* const* d_in, const int* in_sizes, int n_in,
                              void* d_out, int out_size, void* d_ws, size_t ws_size,
                              hipStream_t stream) {
  const float* x   = (const float*)d_in[0];
  const int*   adj = (const int*)d_in[1];
  const float* W0  = (const float*)d_in[2];
  const float* as0 = (const float*)d_in[3];
  const float* ad0 = (const float*)d_in[4];
  const float* b0  = (const float*)d_in[5];
  const float* W1  = (const float*)d_in[6];
  const float* as1 = (const float*)d_in[7];
  const float* ad1 = (const float*)d_in[8];
  const float* b1  = (const float*)d_in[9];
  const float* W2  = (const float*)d_in[10];
  const float* as2 = (const float*)d_in[11];
  const float* ad2 = (const float*)d_in[12];
  const float* b2  = (const float*)d_in[13];
  const float* g0  = (const float*)d_in[14];
  const float* be0 = (const float*)d_in[15];
  const float* g1  = (const float*)d_in[16];
  const float* be1 = (const float*)d_in[17];
  float* out = (float*)d_out;

  float* ws   = (float*)d_ws;
  float* asrc = ws;                                  // N*4
  float* adst = asrc + (size_t)NNODES * 4;           // N*4 (contiguous with asrc)
  float* stat = adst + (size_t)NNODES * 4;           // 512
  float* bnsc = stat + 512;                          // 256
  float* bnsh = bnsc + 256;                          // 256
  u16*   hb   = (u16*)(bnsh + 256);                  // N*256 bf16 (GEMM out / h payload)
  u16*   hbo  = hb + (size_t)NNODES * 256;           // N*256 bf16 (aggr out / next GEMM in)
  u16*   w0t  = hbo + (size_t)NNODES * 256;          // 256*128 bf16 (W0^T)
  u16*   w1t  = w0t + 256 * 128;                     // 256*256 bf16 (W1^T)
  u16*   w2t  = w1t + 256 * 256;                     // 160*256 bf16 (W2^T)
  u16*   ew   = w2t + 160 * 256;                     // EPTOT*4 bf16 (edge weights)
  int* rowptr = (int*)(ew + (size_t)EPTOT * 4);      // N+1
  int* fill   = rowptr + (NNODES + 1);               // N
  int* colx   = fill + NNODES;                       // EPTOT
  int* deg    = colx + EPTOT;                        // N
  int* part   = deg + NNODES;                        // N
  int* bsum   = part + NNODES;                       // SCAN_NB

  // CSR build (by destination), self-loops appended as edges E..E+N-1
  hipMemsetAsync(deg, 0, NNODES * sizeof(int), stream);
  k_hist<<<(EPTOT + 255) / 256, 256, 0, stream>>>(adj, deg);
  k_scan1<<<SCAN_NB, 256, 0, stream>>>(deg, part, bsum);
  k_scan2<<<1, 256, 0, stream>>>(bsum);
  k_scan3<<<SCAN_NB, 256, 0, stream>>>(part, bsum, rowptr, fill);
  k_fill<<<(EPTOT + 255) / 256, 256, 0, stream>>>(adj, fill, colx);

  // weight transpose+convert (tiny)
  k_wt<<<(128 * 256 + 255) / 256, 256, 0, stream>>>(W0, w0t, 128, 256);
  k_wt<<<(256 * 256 + 255) / 256, 256, 0, stream>>>(W1, w1t, 256, 256);
  k_wt<<<(256 * 160 + 255) / 256, 256, 0, stream>>>(W2, w2t, 256, 160);

  dim3 gg2((NNODES + 127) / 128, 2);

  // layer 0 (K=128, f32 A, fused att)
  hipMemsetAsync(asrc, 0, (size_t)NNODES * 8 * sizeof(float), stream);
  k_gemm_mfma<0, 1><<<gg2, 256, 0, stream>>>(x, w0t, hb, nullptr, nullptr,
                                             as0, ad0, asrc, adst, NNODES, 128, 256);
  k_aggr_hid<<<12500, 256, 0, stream>>>(hb, asrc, adst, rowptr, colx, b0, ew, hbo);
  hipMemsetAsync(stat, 0, 512 * sizeof(float), stream);
  k_bnstats<<<400, 256, 0, stream>>>(hbo, stat);
  k_bnfin<<<1, 256, 0, stream>>>(stat, g0, be0, bnsc, bnsh);

  // layer 1 (K=256, bf16 A + fused BN0+LeakyReLU, fused att)
  hipMemsetAsync(asrc, 0, (size_t)NNODES * 8 * sizeof(float), stream);
  k_gemm_mfma<1, 1><<<gg2, 256, 0, stream>>>(hbo, w1t, hb, bnsc, bnsh,
                                             as1, ad1, asrc, adst, NNODES, 256, 256);
  k_aggr_hid<<<12500, 256, 0, stream>>>(hb, asrc, adst, rowptr, colx, b1, ew, hbo);
  hipMemsetAsync(stat, 0, 512 * sizeof(float), stream);
  k_bnstats<<<400, 256, 0, stream>>>(hbo, stat);
  k_bnfin<<<1, 256, 0, stream>>>(stat, g1, be1, bnsc, bnsh);

  // layer 2 (K=256, Nc=160, bf16 A + fused BN1+LeakyReLU) + att_l2 + log_softmax
  k_gemm_mfma<1, 0><<<gg2, 256, 0, stream>>>(hbo, w2t, hb, bnsc, bnsh,
                                             nullptr, nullptr, nullptr, nullptr,
                                             NNODES, 256, 160);
  k_att_l2<<<12500, 256, 0, stream>>>(hb, as2, ad2, asrc, adst);
  k_aggr_l2<<<12500, 256, 0, stream>>>(hb, asrc, adst, rowptr, colx, b2, ew, out);
}